// Round 9
// baseline (286.713 us; speedup 1.0000x reference)
//
#include <hip/hip_runtime.h>
#include <hip/hip_bf16.h>

// HeteroGCN: 3x SAGEConv(mean).
// R1: CSR + gather aggregation (no output atomics).
// R2: hierarchical scan over concatenated degree counters.
// R3: bf16 MFMA GEMM with K-concatenation, packed weights, single pass per output.
// R4: bf16 gene feature table; unrolled gather.
// R5: 16-lane-group-per-node gather; bf16 trait table.
// R6: CSR build via two-phase LDS binning (coalesced, few atomics).
// R7: fused agg over all 300k dst nodes, 4-deep clamped gather.
// R8: gather-mean FUSED into the MFMA GEMM: 2 lanes per dst row accumulate the
//     row's 64 features each (8x uint4 in flight, pk_add f32 pairs) directly in
//     a-fragment layout -> no agg buffers (kills 75MB write + 75MB re-read +
//     one dependency). One cvt launch for both feature tables.

#define D 128
#define NG 100000
#define NT 100000
#define NSEG (NG + NT + NG)   // concatenated dst-node counters: gg | gt | tg

#define NBUCK 256
#define NPB   ((NSEG + NBUCK - 1) / NBUCK)   // 1172 seg-nodes per bucket
#define TILE  4096                            // edges per bscatter workgroup

typedef __bf16 bf16x8 __attribute__((ext_vector_type(8)));
typedef float f32x16 __attribute__((ext_vector_type(16)));
typedef float v2f __attribute__((ext_vector_type(2)));

static __device__ __forceinline__ unsigned short f2bf(float f) {
    return __builtin_bit_cast(unsigned short, (__bf16)f);
}
static __device__ __forceinline__ float bflo(unsigned int v) {
    return __builtin_bit_cast(float, v << 16);
}
static __device__ __forceinline__ float bfhi(unsigned int v) {
    return __builtin_bit_cast(float, v & 0xffff0000u);
}

// ---------------- fp32 -> bf16 feature tables (both in one launch) ----------------
__global__ __launch_bounds__(256) void cvt2_kernel(
    const float* __restrict__ xg, const float* __restrict__ xt,
    unsigned short* __restrict__ og, unsigned short* __restrict__ ot)
{
    const int i = blockIdx.x * 256 + threadIdx.x;
    const int ng8 = NG * D / 8;
    const int nt8 = NT * D / 8;
    if (i >= ng8 + nt8) return;
    const float* x; unsigned short* o; int j;
    if (i < ng8) { x = xg; o = og; j = i; }
    else         { x = xt; o = ot; j = i - ng8; }
    const float4 f0 = ((const float4*)x)[j * 2];
    const float4 f1 = ((const float4*)x)[j * 2 + 1];
    uint4 v;
    v.x = (unsigned int)f2bf(f0.x) | ((unsigned int)f2bf(f0.y) << 16);
    v.y = (unsigned int)f2bf(f0.z) | ((unsigned int)f2bf(f0.w) << 16);
    v.z = (unsigned int)f2bf(f1.x) | ((unsigned int)f2bf(f1.y) << 16);
    v.w = (unsigned int)f2bf(f1.z) | ((unsigned int)f2bf(f1.w) << 16);
    ((uint4*)o)[j] = v;
}

// ---------------- weight pack + bias fold ----------------
// B-frag slot (kt, nt, lane, j) holds W[kt*16 + (lane>>5)*8 + j][nt*32 + (lane&31)]
__global__ __launch_bounds__(256) void prep_kernel(
    const float* __restrict__ Ws_gg, const float* __restrict__ Ws_tg,
    const float* __restrict__ Wn_gg, const float* __restrict__ Wn_tg,
    const float* __restrict__ Ws_gt, const float* __restrict__ Wn_gt,
    const float* __restrict__ b_gg, const float* __restrict__ b_tg,
    const float* __restrict__ b_gt,
    unsigned short* __restrict__ WpG, unsigned short* __restrict__ WpT,
    float* __restrict__ biasG, float* __restrict__ biasT)
{
    const int gid = blockIdx.x * 256 + threadIdx.x;
    if (gid < 6144) {                       // gene pack: 24 kt * 4 nt * 64 lanes
        const int lane = gid & 63, nt = (gid >> 6) & 3, kt = gid >> 8;
        const int n = nt * 32 + (lane & 31);
        const int kb = kt * 16 + (lane >> 5) * 8;
        unsigned int pk[4];
#pragma unroll
        for (int jj = 0; jj < 4; ++jj) {
            unsigned int w2 = 0;
#pragma unroll
            for (int h = 0; h < 2; ++h) {
                const int k = kb + jj * 2 + h;
                float w;
                if (k < 128)      w = Ws_gg[k * D + n] + Ws_tg[k * D + n];
                else if (k < 256) w = Wn_gg[(k - 128) * D + n];
                else              w = Wn_tg[(k - 256) * D + n];
                w2 |= ((unsigned int)f2bf(w)) << (16 * h);
            }
            pk[jj] = w2;
        }
        *(uint4*)(WpG + (size_t)gid * 8) = make_uint4(pk[0], pk[1], pk[2], pk[3]);
    } else if (gid < 6144 + 4096) {         // trait pack: 16 kt * 4 nt * 64 lanes
        const int g = gid - 6144;
        const int lane = g & 63, nt = (g >> 6) & 3, kt = g >> 8;
        const int n = nt * 32 + (lane & 31);
        const int kb = kt * 16 + (lane >> 5) * 8;
        unsigned int pk[4];
#pragma unroll
        for (int jj = 0; jj < 4; ++jj) {
            unsigned int w2 = 0;
#pragma unroll
            for (int h = 0; h < 2; ++h) {
                const int k = kb + jj * 2 + h;
                const float w = (k < 128) ? Ws_gt[k * D + n] : Wn_gt[(k - 128) * D + n];
                w2 |= ((unsigned int)f2bf(w)) << (16 * h);
            }
            pk[jj] = w2;
        }
        *(uint4*)(WpT + (size_t)g * 8) = make_uint4(pk[0], pk[1], pk[2], pk[3]);
    } else if (gid < 6144 + 4096 + 128) {
        const int i = gid - (6144 + 4096);
        biasG[i] = b_gg[i] + b_tg[i];
    } else if (gid < 6144 + 4096 + 256) {
        const int i = gid - (6144 + 4096 + 128);
        biasT[i] = b_gt[i];
    }
}

// ---------------- binning phase A ----------------
static __device__ __forceinline__ int edge_seg(
    int ge, const int* d0, int n0, const int* d1, int n1, const int* d2)
{
    if (ge < n0) return d0[ge];
    if (ge < n0 + n1) return NG + d1[ge - n0];
    return NG + NT + d2[ge - n0 - n1];
}
static __device__ __forceinline__ int edge_src(
    int ge, const int* s0, int n0, const int* s1, int n1, const int* s2)
{
    if (ge < n0) return s0[ge];
    if (ge < n0 + n1) return s1[ge - n0];
    return s2[ge - n0 - n1];
}

// A1: per-bucket histogram (LDS hist per WG -> 256 global adds)
__global__ __launch_bounds__(256) void bcount_kernel(
    const int* __restrict__ d0, int n0, const int* __restrict__ d1, int n1,
    const int* __restrict__ d2, int nE, int* __restrict__ bcount)
{
    __shared__ int hist[NBUCK];
    const int t = threadIdx.x;
    hist[t] = 0;
    __syncthreads();
    const int base = blockIdx.x * TILE;
#pragma unroll
    for (int j = 0; j < TILE / 256; ++j) {
        const int ge = base + j * 256 + t;
        if (ge < nE) {
            const int seg = edge_seg(ge, d0, n0, d1, n1, d2);
            atomicAdd(&hist[seg / NPB], 1);
        }
    }
    __syncthreads();
    if (hist[t]) atomicAdd(&bcount[t], hist[t]);
}

// A2: exclusive scan of 256 bucket counts -> base[257], cursor init, off[NSEG]
__global__ __launch_bounds__(256) void bscan_kernel(
    const int* __restrict__ bcount, int* __restrict__ bbase,
    int* __restrict__ bcursor, int* __restrict__ off)
{
    __shared__ int lds[NBUCK];
    const int t = threadIdx.x;
    const int v = bcount[t];
    lds[t] = v;
    __syncthreads();
    for (int sh = 1; sh < NBUCK; sh <<= 1) {
        int u = (t >= sh) ? lds[t - sh] : 0;
        __syncthreads();
        lds[t] += u;
        __syncthreads();
    }
    const int excl = lds[t] - v;
    bbase[t] = excl;
    bcursor[t] = excl;
    if (t == NBUCK - 1) {
        bbase[NBUCK] = lds[t];
        off[NSEG] = lds[t];
    }
}

// A3: LDS multi-split scatter: stage tile, reorder by bucket, reserve global
// space with ONE atomic per bucket per WG, dump bucket-contiguous (src,seg).
__global__ __launch_bounds__(256) void bscatter_kernel(
    const int* __restrict__ s0, const int* __restrict__ d0, int n0,
    const int* __restrict__ s1, const int* __restrict__ d1, int n1,
    const int* __restrict__ s2, const int* __restrict__ d2, int nE,
    int* __restrict__ bcursor, int2* __restrict__ binned)
{
    __shared__ int2 stage[TILE];
    __shared__ int hist[NBUCK], scn[NBUCK], gbase[NBUCK], lcur[NBUCK];
    const int t = threadIdx.x;
    hist[t] = 0;
    __syncthreads();

    const int base = blockIdx.x * TILE;
    int mseg[TILE / 256], msrc[TILE / 256];
#pragma unroll
    for (int j = 0; j < TILE / 256; ++j) {
        const int ge = base + j * 256 + t;
        if (ge < nE) {
            mseg[j] = edge_seg(ge, d0, n0, d1, n1, d2);
            msrc[j] = edge_src(ge, s0, n0, s1, n1, s2);
            atomicAdd(&hist[mseg[j] / NPB], 1);
        } else mseg[j] = -1;
    }
    __syncthreads();

    const int h = hist[t];
    scn[t] = h;
    __syncthreads();
    for (int sh = 1; sh < NBUCK; sh <<= 1) {
        int u = (t >= sh) ? scn[t - sh] : 0;
        __syncthreads();
        scn[t] += u;
        __syncthreads();
    }
    const int excl = scn[t] - h;
    __syncthreads();
    scn[t] = excl;
    lcur[t] = excl;
    if (h) gbase[t] = atomicAdd(&bcursor[t], h);
    __syncthreads();

#pragma unroll
    for (int j = 0; j < TILE / 256; ++j) {
        if (mseg[j] >= 0) {
            const int b = mseg[j] / NPB;
            const int pos = atomicAdd(&lcur[b], 1);
            stage[pos] = make_int2(msrc[j], mseg[j]);
        }
    }
    __syncthreads();

    const int cnt = min(TILE, nE - base);
    for (int slot = t; slot < cnt; slot += 256) {
        const int2 pr = stage[slot];
        const int b = pr.y / NPB;
        binned[gbase[b] + (slot - scn[b])] = pr;
    }
}

// B: one WG per bucket. Per-node degree + scan + scatter entirely in LDS.
__global__ __launch_bounds__(256) void bbuild_kernel(
    const int2* __restrict__ binned, const int* __restrict__ bbase,
    int* __restrict__ off, int* __restrict__ sorted)
{
    constexpr int CH = (NPB + 255) / 256;   // 5
    __shared__ int ldeg[NPB];
    __shared__ int loff[NPB];
    __shared__ int psum[256];
    const int t = threadIdx.x;
    const int b = blockIdx.x;
    const int n0 = b * NPB;
    const int NL = min(NSEG - n0, NPB);
    const int ebase = bbase[b];
    const int ecnt = bbase[b + 1] - ebase;

    for (int i = t; i < NL; i += 256) ldeg[i] = 0;
    __syncthreads();
    for (int e = t; e < ecnt; e += 256)
        atomicAdd(&ldeg[binned[ebase + e].y - n0], 1);
    __syncthreads();

    int s = 0;
#pragma unroll
    for (int k = 0; k < CH; ++k) {
        const int i = t * CH + k;
        if (i < NL) s += ldeg[i];
    }
    psum[t] = s;
    __syncthreads();
    for (int sh = 1; sh < 256; sh <<= 1) {
        int u = (t >= sh) ? psum[t - sh] : 0;
        __syncthreads();
        psum[t] += u;
        __syncthreads();
    }
    int run = psum[t] - s;
#pragma unroll
    for (int k = 0; k < CH; ++k) {
        const int i = t * CH + k;
        if (i < NL) { loff[i] = run; run += ldeg[i]; }
    }
    __syncthreads();

    for (int i = t; i < NL; i += 256) off[n0 + i] = ebase + loff[i];
    __syncthreads();

    for (int e = t; e < ecnt; e += 256) {
        const int2 pr = binned[ebase + e];
        const int slot = atomicAdd(&loff[pr.y - n0], 1);
        sorted[ebase + slot] = pr.x;
    }
}

// ---------------- fused gather-mean + MFMA GEMM ----------------
// 256 threads = 4 waves, each wave one 32-row dst tile.
// Source 0 = self (bf16 table, frags read directly). Sources 1..NSRC-1:
// each of the 2 lanes covering dst row lm gathers+means its own 64 features
// (8x uint4 per neighbor, accumulated as float2 pairs) -> result is already
// in a-fragment layout; cvt to bf16 and MFMA against the LDS-staged W slice.
#define ACC4(kt, V) \
    ga[kt][0] += (v2f){bflo((V).x), bfhi((V).x)}; \
    ga[kt][1] += (v2f){bflo((V).y), bfhi((V).y)}; \
    ga[kt][2] += (v2f){bflo((V).z), bfhi((V).z)}; \
    ga[kt][3] += (v2f){bflo((V).w), bfhi((V).w)};

template<int NSRC>
__global__ __launch_bounds__(256) void gemm_fused(
    const unsigned short* __restrict__ Aself,
    const unsigned short* __restrict__ Xg1,
    const unsigned short* __restrict__ Xg2,
    const int* __restrict__ off, const int* __restrict__ sorted,
    int seg1, int seg2,
    const unsigned short* __restrict__ Wpack, const float* __restrict__ bias,
    float* __restrict__ out, int M)
{
    __shared__ unsigned short WL[8 * 4 * 64 * 8];   // 32 KiB: one source slice
    const int t = threadIdx.x;
    const int wid = t >> 6, lane = t & 63;
    const int lm = lane & 31, l5 = lane >> 5;
    const int tile = blockIdx.x * 4 + wid;
    const bool active = tile * 32 < M;
    const int m = tile * 32 + lm;

    f32x16 acc[4];
    if (active) {
#pragma unroll
        for (int nt = 0; nt < 4; ++nt) {
#pragma unroll
            for (int q = 0; q < 4; ++q) {
                const float4 bq = *(const float4*)&bias[nt * 32 + 4 * l5 + 8 * q];
                acc[nt][4 * q + 0] = bq.x; acc[nt][4 * q + 1] = bq.y;
                acc[nt][4 * q + 2] = bq.z; acc[nt][4 * q + 3] = bq.w;
            }
        }
    }

    const uint4* wg = (const uint4*)Wpack;
    uint4* wl = (uint4*)WL;

#pragma unroll 1
    for (int s = 0; s < NSRC; ++s) {
        __syncthreads();
#pragma unroll
        for (int i = 0; i < 8; ++i)
            wl[t + i * 256] = wg[(size_t)s * 2048 + t + i * 256];
        __syncthreads();
        if (!active) continue;

        if (s == 0) {
            const unsigned short* ar = Aself + (size_t)m * D + l5 * 8;
#pragma unroll
            for (int kt = 0; kt < 8; ++kt) {
                const bf16x8 a = *(const bf16x8*)(ar + kt * 16);
#pragma unroll
                for (int nt = 0; nt < 4; ++nt) {
                    const bf16x8 b = *(const bf16x8*)&WL[((kt * 4 + nt) * 64 + lane) * 8];
                    acc[nt] = __builtin_amdgcn_mfma_f32_32x32x16_bf16(b, a, acc[nt], 0, 0, 0);
                }
            }
        } else {
            const unsigned short* xs = (s == 1) ? Xg1 : Xg2;
            const int segb = (s == 1) ? seg1 : seg2;
            const int s0 = off[segb + m];
            const int s1 = off[segb + m + 1];

            v2f ga[8][4];
#pragma unroll
            for (int kt = 0; kt < 8; ++kt)
#pragma unroll
                for (int j = 0; j < 4; ++j) ga[kt][j] = (v2f){0.f, 0.f};

            for (int e = s0; e < s1; ++e) {
                const unsigned short* xr = xs + (size_t)sorted[e] * D + l5 * 8;
                // batch 1: chunks 0..3 (4 loads in flight)
                const uint4 v0 = *(const uint4*)(xr);
                const uint4 v1 = *(const uint4*)(xr + 16);
                const uint4 v2 = *(const uint4*)(xr + 32);
                const uint4 v3 = *(const uint4*)(xr + 48);
                ACC4(0, v0) ACC4(1, v1) ACC4(2, v2) ACC4(3, v3)
                // batch 2: chunks 4..7
                const uint4 v4 = *(const uint4*)(xr + 64);
                const uint4 v5 = *(const uint4*)(xr + 80);
                const uint4 v6 = *(const uint4*)(xr + 96);
                const uint4 v7 = *(const uint4*)(xr + 112);
                ACC4(4, v4) ACC4(5, v5) ACC4(6, v6) ACC4(7, v7)
            }

            const float inv = 1.0f / (float)max(s1 - s0, 1);
#pragma unroll
            for (int kt = 0; kt < 8; ++kt) {
                bf16x8 a;
                a[0] = (__bf16)(ga[kt][0].x * inv); a[1] = (__bf16)(ga[kt][0].y * inv);
                a[2] = (__bf16)(ga[kt][1].x * inv); a[3] = (__bf16)(ga[kt][1].y * inv);
                a[4] = (__bf16)(ga[kt][2].x * inv); a[5] = (__bf16)(ga[kt][2].y * inv);
                a[6] = (__bf16)(ga[kt][3].x * inv); a[7] = (__bf16)(ga[kt][3].y * inv);
#pragma unroll
                for (int nt = 0; nt < 4; ++nt) {
                    const bf16x8 b = *(const bf16x8*)&WL[((kt * 4 + nt) * 64 + lane) * 8];
                    acc[nt] = __builtin_amdgcn_mfma_f32_32x32x16_bf16(b, a, acc[nt], 0, 0, 0);
                }
            }
        }
    }

    if (active) {
        float* orow = out + (size_t)m * D;
#pragma unroll
        for (int nt = 0; nt < 4; ++nt) {
            float* p = orow + nt * 32 + 4 * l5;
            *(float4*)(p + 0)  = make_float4(acc[nt][0],  acc[nt][1],  acc[nt][2],  acc[nt][3]);
            *(float4*)(p + 8)  = make_float4(acc[nt][4],  acc[nt][5],  acc[nt][6],  acc[nt][7]);
            *(float4*)(p + 16) = make_float4(acc[nt][8],  acc[nt][9],  acc[nt][10], acc[nt][11]);
            *(float4*)(p + 24) = make_float4(acc[nt][12], acc[nt][13], acc[nt][14], acc[nt][15]);
        }
    }
}

extern "C" void kernel_launch(void* const* d_in, const int* in_sizes, int n_in,
                              void* d_out, int out_size, void* d_ws, size_t ws_size,
                              hipStream_t stream)
{
    const float* x_gene  = (const float*)d_in[0];
    const float* x_trait = (const float*)d_in[1];
    const int* src_gg = (const int*)d_in[2];
    const int* dst_gg = (const int*)d_in[3];
    const int* src_gt = (const int*)d_in[4];
    const int* dst_gt = (const int*)d_in[5];
    const int* src_tg = (const int*)d_in[6];
    const int* dst_tg = (const int*)d_in[7];
    const float* Wn_gg = (const float*)d_in[8];
    const float* Ws_gg = (const float*)d_in[9];
    const float* b_gg  = (const float*)d_in[10];
    const float* Wn_gt = (const float*)d_in[11];
    const float* Ws_gt = (const float*)d_in[12];
    const float* b_gt  = (const float*)d_in[13];
    const float* Wn_tg = (const float*)d_in[14];
    const float* Ws_tg = (const float*)d_in[15];
    const float* b_tg  = (const float*)d_in[16];

    const int nE_gg = in_sizes[2];
    const int nE_gt = in_sizes[4];
    const int nE_tg = in_sizes[6];
    const int nE_total = nE_gg + nE_gt + nE_tg;

    float* out_gene  = (float*)d_out;
    float* out_trait = (float*)d_out + (size_t)NG * D;

    // ws: xb_gene | xb_trait | WpG | WpT | biasG | biasT | off | bcount |
    //     bbase | bcursor | sorted | binned     (~70 MB total)
    unsigned short* xb_gene  = (unsigned short*)d_ws;
    unsigned short* xb_trait = xb_gene + (size_t)NG * D;
    char* p = (char*)(xb_trait + (size_t)NT * D);
    unsigned short* WpG = (unsigned short*)p;  p += 24 * 4 * 64 * 8 * sizeof(unsigned short);
    unsigned short* WpT = (unsigned short*)p;  p += 16 * 4 * 64 * 8 * sizeof(unsigned short);
    float* biasG = (float*)p;                  p += D * sizeof(float);
    float* biasT = (float*)p;                  p += D * sizeof(float);
    int* off     = (int*)p;                    p += (size_t)(NSEG + 1) * sizeof(int);
    int* bcount  = (int*)p;                    p += NBUCK * sizeof(int);
    int* bbase   = (int*)p;                    p += (NBUCK + 1) * sizeof(int);
    int* bcursor = (int*)p;                    p += NBUCK * sizeof(int);
    int* sorted  = (int*)p;                    p += (size_t)nE_total * sizeof(int);
    int2* binned = (int2*)p;

    // weight pack + bias fold; bf16 feature tables (one launch for both)
    prep_kernel<<<41, 256, 0, stream>>>(Ws_gg, Ws_tg, Wn_gg, Wn_tg, Ws_gt, Wn_gt,
                                        b_gg, b_tg, b_gt, WpG, WpT, biasG, biasT);
    cvt2_kernel<<<((NG + NT) * D / 8 + 255) / 256, 256, 0, stream>>>(
        x_gene, x_trait, xb_gene, xb_trait);

    // CSR build via two-phase binning
    const int nWG = (nE_total + TILE - 1) / TILE;
    hipMemsetAsync(bcount, 0, NBUCK * sizeof(int), stream);
    bcount_kernel<<<nWG, 256, 0, stream>>>(dst_gg, nE_gg, dst_gt, nE_gt, dst_tg,
                                           nE_total, bcount);
    bscan_kernel<<<1, 256, 0, stream>>>(bcount, bbase, bcursor, off);
    bscatter_kernel<<<nWG, 256, 0, stream>>>(
        src_gg, dst_gg, nE_gg, src_gt, dst_gt, nE_gt, src_tg, dst_tg,
        nE_total, bcursor, binned);
    bbuild_kernel<<<NBUCK, 256, 0, stream>>>(binned, bbase, off, sorted);

    // fused gather-mean + GEMM, one overwrite pass per output
    const int gblocks = ((NG + 31) / 32 + 3) / 4;   // 782
    const int tblocks = ((NT + 31) / 32 + 3) / 4;

    // gene out: self + gg-agg (from gene table, seg base 0) + tg-agg (trait table, seg NG+NT)
    gemm_fused<3><<<gblocks, 256, 0, stream>>>(
        xb_gene, xb_gene, xb_trait, off, sorted, 0, NG + NT,
        WpG, biasG, out_gene, NG);
    // trait out: self + gt-agg (from gene table, seg base NG)
    gemm_fused<2><<<tblocks, 256, 0, stream>>>(
        xb_trait, xb_gene, nullptr, off, sorted, NG, 0,
        WpT, biasT, out_trait, NT);
}

// Round 10
// 204.172 us; speedup vs baseline: 1.4043x; 1.4043x over previous
//
#include <hip/hip_runtime.h>
#include <hip/hip_bf16.h>

// HeteroGCN: 3x SAGEConv(mean).
// R1-R8: CSR gather (no atomics), two-phase LDS binning CSR build, bf16 MFMA
//        GEMM with K-concat + packed weights, bf16 feature tables, fused agg.
// R9 (failed): agg-in-GEMM fusion -> 8% occupancy, reverted.
// R10: R8 split structure + agg index-broadcast: 16 lanes fetch 16 edge
//      indices in ONE coalesced load, __shfl-broadcast (no idx round-trip per
//      chunk), zero-row padding for tail lanes (L1-hot). One GEMM launch for
//      both outputs; trait table always bf16.

#define D 128
#define NG 100000
#define NT 100000
#define NSEG (NG + NT + NG)   // concatenated dst-node counters: gg | gt | tg

#define NBUCK 256
#define NPB   ((NSEG + NBUCK - 1) / NBUCK)   // 1172 seg-nodes per bucket
#define TILE  4096                            // edges per bscatter workgroup

typedef __bf16 bf16x8 __attribute__((ext_vector_type(8)));
typedef float f32x16 __attribute__((ext_vector_type(16)));

static __device__ __forceinline__ unsigned short f2bf(float f) {
    return __builtin_bit_cast(unsigned short, (__bf16)f);
}
static __device__ __forceinline__ float bflo(unsigned int v) {
    return __builtin_bit_cast(float, v << 16);
}
static __device__ __forceinline__ float bfhi(unsigned int v) {
    return __builtin_bit_cast(float, v & 0xffff0000u);
}

// ---------------- fp32 -> bf16 feature tables (+1 zero row each) ----------------
__global__ __launch_bounds__(256) void cvt2_kernel(
    const float* __restrict__ xg, const float* __restrict__ xt,
    unsigned short* __restrict__ og, unsigned short* __restrict__ ot)
{
    const int i = blockIdx.x * 256 + threadIdx.x;
    const int ng8 = (NG + 1) * D / 8;   // incl. zero row
    const int nt8 = (NT + 1) * D / 8;
    if (i >= ng8 + nt8) return;
    const float* x; unsigned short* o; int j, nreal8;
    if (i < ng8) { x = xg; o = og; j = i;       nreal8 = NG * D / 8; }
    else         { x = xt; o = ot; j = i - ng8; nreal8 = NT * D / 8; }
    uint4 v = make_uint4(0, 0, 0, 0);
    if (j < nreal8) {
        const float4 f0 = ((const float4*)x)[j * 2];
        const float4 f1 = ((const float4*)x)[j * 2 + 1];
        v.x = (unsigned int)f2bf(f0.x) | ((unsigned int)f2bf(f0.y) << 16);
        v.y = (unsigned int)f2bf(f0.z) | ((unsigned int)f2bf(f0.w) << 16);
        v.z = (unsigned int)f2bf(f1.x) | ((unsigned int)f2bf(f1.y) << 16);
        v.w = (unsigned int)f2bf(f1.z) | ((unsigned int)f2bf(f1.w) << 16);
    }
    ((uint4*)o)[j] = v;
}

// ---------------- weight pack + bias fold ----------------
// B-frag slot (kt, nt, lane, j) holds W[kt*16 + (lane>>5)*8 + j][nt*32 + (lane&31)]
__global__ __launch_bounds__(256) void prep_kernel(
    const float* __restrict__ Ws_gg, const float* __restrict__ Ws_tg,
    const float* __restrict__ Wn_gg, const float* __restrict__ Wn_tg,
    const float* __restrict__ Ws_gt, const float* __restrict__ Wn_gt,
    const float* __restrict__ b_gg, const float* __restrict__ b_tg,
    const float* __restrict__ b_gt,
    unsigned short* __restrict__ WpG, unsigned short* __restrict__ WpT,
    float* __restrict__ biasG, float* __restrict__ biasT)
{
    const int gid = blockIdx.x * 256 + threadIdx.x;
    if (gid < 6144) {                       // gene pack: 24 kt * 4 nt * 64 lanes
        const int lane = gid & 63, nt = (gid >> 6) & 3, kt = gid >> 8;
        const int n = nt * 32 + (lane & 31);
        const int kb = kt * 16 + (lane >> 5) * 8;
        unsigned int pk[4];
#pragma unroll
        for (int jj = 0; jj < 4; ++jj) {
            unsigned int w2 = 0;
#pragma unroll
            for (int h = 0; h < 2; ++h) {
                const int k = kb + jj * 2 + h;
                float w;
                if (k < 128)      w = Ws_gg[k * D + n] + Ws_tg[k * D + n];
                else if (k < 256) w = Wn_gg[(k - 128) * D + n];
                else              w = Wn_tg[(k - 256) * D + n];
                w2 |= ((unsigned int)f2bf(w)) << (16 * h);
            }
            pk[jj] = w2;
        }
        *(uint4*)(WpG + (size_t)gid * 8) = make_uint4(pk[0], pk[1], pk[2], pk[3]);
    } else if (gid < 6144 + 4096) {         // trait pack: 16 kt * 4 nt * 64 lanes
        const int g = gid - 6144;
        const int lane = g & 63, nt = (g >> 6) & 3, kt = g >> 8;
        const int n = nt * 32 + (lane & 31);
        const int kb = kt * 16 + (lane >> 5) * 8;
        unsigned int pk[4];
#pragma unroll
        for (int jj = 0; jj < 4; ++jj) {
            unsigned int w2 = 0;
#pragma unroll
            for (int h = 0; h < 2; ++h) {
                const int k = kb + jj * 2 + h;
                const float w = (k < 128) ? Ws_gt[k * D + n] : Wn_gt[(k - 128) * D + n];
                w2 |= ((unsigned int)f2bf(w)) << (16 * h);
            }
            pk[jj] = w2;
        }
        *(uint4*)(WpT + (size_t)g * 8) = make_uint4(pk[0], pk[1], pk[2], pk[3]);
    } else if (gid < 6144 + 4096 + 128) {
        const int i = gid - (6144 + 4096);
        biasG[i] = b_gg[i] + b_tg[i];
    } else if (gid < 6144 + 4096 + 256) {
        const int i = gid - (6144 + 4096 + 128);
        biasT[i] = b_gt[i];
    }
}

// ---------------- binning (CSR build) ----------------
static __device__ __forceinline__ int edge_seg(
    int ge, const int* d0, int n0, const int* d1, int n1, const int* d2)
{
    if (ge < n0) return d0[ge];
    if (ge < n0 + n1) return NG + d1[ge - n0];
    return NG + NT + d2[ge - n0 - n1];
}
static __device__ __forceinline__ int edge_src(
    int ge, const int* s0, int n0, const int* s1, int n1, const int* s2)
{
    if (ge < n0) return s0[ge];
    if (ge < n0 + n1) return s1[ge - n0];
    return s2[ge - n0 - n1];
}

__global__ __launch_bounds__(256) void bcount_kernel(
    const int* __restrict__ d0, int n0, const int* __restrict__ d1, int n1,
    const int* __restrict__ d2, int nE, int* __restrict__ bcount)
{
    __shared__ int hist[NBUCK];
    const int t = threadIdx.x;
    hist[t] = 0;
    __syncthreads();
    const int base = blockIdx.x * TILE;
#pragma unroll
    for (int j = 0; j < TILE / 256; ++j) {
        const int ge = base + j * 256 + t;
        if (ge < nE) {
            const int seg = edge_seg(ge, d0, n0, d1, n1, d2);
            atomicAdd(&hist[seg / NPB], 1);
        }
    }
    __syncthreads();
    if (hist[t]) atomicAdd(&bcount[t], hist[t]);
}

__global__ __launch_bounds__(256) void bscan_kernel(
    const int* __restrict__ bcount, int* __restrict__ bbase,
    int* __restrict__ bcursor, int* __restrict__ off)
{
    __shared__ int lds[NBUCK];
    const int t = threadIdx.x;
    const int v = bcount[t];
    lds[t] = v;
    __syncthreads();
    for (int sh = 1; sh < NBUCK; sh <<= 1) {
        int u = (t >= sh) ? lds[t - sh] : 0;
        __syncthreads();
        lds[t] += u;
        __syncthreads();
    }
    const int excl = lds[t] - v;
    bbase[t] = excl;
    bcursor[t] = excl;
    if (t == NBUCK - 1) {
        bbase[NBUCK] = lds[t];
        off[NSEG] = lds[t];
    }
}

__global__ __launch_bounds__(256) void bscatter_kernel(
    const int* __restrict__ s0, const int* __restrict__ d0, int n0,
    const int* __restrict__ s1, const int* __restrict__ d1, int n1,
    const int* __restrict__ s2, const int* __restrict__ d2, int nE,
    int* __restrict__ bcursor, int2* __restrict__ binned)
{
    __shared__ int2 stage[TILE];
    __shared__ int hist[NBUCK], scn[NBUCK], gbase[NBUCK], lcur[NBUCK];
    const int t = threadIdx.x;
    hist[t] = 0;
    __syncthreads();

    const int base = blockIdx.x * TILE;
    int mseg[TILE / 256], msrc[TILE / 256];
#pragma unroll
    for (int j = 0; j < TILE / 256; ++j) {
        const int ge = base + j * 256 + t;
        if (ge < nE) {
            mseg[j] = edge_seg(ge, d0, n0, d1, n1, d2);
            msrc[j] = edge_src(ge, s0, n0, s1, n1, s2);
            atomicAdd(&hist[mseg[j] / NPB], 1);
        } else mseg[j] = -1;
    }
    __syncthreads();

    const int h = hist[t];
    scn[t] = h;
    __syncthreads();
    for (int sh = 1; sh < NBUCK; sh <<= 1) {
        int u = (t >= sh) ? scn[t - sh] : 0;
        __syncthreads();
        scn[t] += u;
        __syncthreads();
    }
    const int excl = scn[t] - h;
    __syncthreads();
    scn[t] = excl;
    lcur[t] = excl;
    if (h) gbase[t] = atomicAdd(&bcursor[t], h);
    __syncthreads();

#pragma unroll
    for (int j = 0; j < TILE / 256; ++j) {
        if (mseg[j] >= 0) {
            const int b = mseg[j] / NPB;
            const int pos = atomicAdd(&lcur[b], 1);
            stage[pos] = make_int2(msrc[j], mseg[j]);
        }
    }
    __syncthreads();

    const int cnt = min(TILE, nE - base);
    for (int slot = t; slot < cnt; slot += 256) {
        const int2 pr = stage[slot];
        const int b = pr.y / NPB;
        binned[gbase[b] + (slot - scn[b])] = pr;
    }
}

__global__ __launch_bounds__(256) void bbuild_kernel(
    const int2* __restrict__ binned, const int* __restrict__ bbase,
    int* __restrict__ off, int* __restrict__ sorted)
{
    constexpr int CH = (NPB + 255) / 256;   // 5
    __shared__ int ldeg[NPB];
    __shared__ int loff[NPB];
    __shared__ int psum[256];
    const int t = threadIdx.x;
    const int b = blockIdx.x;
    const int n0 = b * NPB;
    const int NL = min(NSEG - n0, NPB);
    const int ebase = bbase[b];
    const int ecnt = bbase[b + 1] - ebase;

    for (int i = t; i < NL; i += 256) ldeg[i] = 0;
    __syncthreads();
    for (int e = t; e < ecnt; e += 256)
        atomicAdd(&ldeg[binned[ebase + e].y - n0], 1);
    __syncthreads();

    int s = 0;
#pragma unroll
    for (int k = 0; k < CH; ++k) {
        const int i = t * CH + k;
        if (i < NL) s += ldeg[i];
    }
    psum[t] = s;
    __syncthreads();
    for (int sh = 1; sh < 256; sh <<= 1) {
        int u = (t >= sh) ? psum[t - sh] : 0;
        __syncthreads();
        psum[t] += u;
        __syncthreads();
    }
    int run = psum[t] - s;
#pragma unroll
    for (int k = 0; k < CH; ++k) {
        const int i = t * CH + k;
        if (i < NL) { loff[i] = run; run += ldeg[i]; }
    }
    __syncthreads();

    for (int i = t; i < NL; i += 256) off[n0 + i] = ebase + loff[i];
    __syncthreads();

    for (int e = t; e < ecnt; e += 256) {
        const int2 pr = binned[ebase + e];
        const int slot = atomicAdd(&loff[pr.y - n0], 1);
        sorted[ebase + slot] = pr.x;
    }
}

// ---------------- aggregation: idx-broadcast gather ----------------
// 256 threads = 16 nodes/block; 16-lane group per node, lane covers 8 cols.
// Per 16-edge batch: ONE coalesced 16-lane index load, then __shfl broadcast
// feeds up to 16 independent row loads. Tail lanes read the zero row (L1-hot).
__global__ __launch_bounds__(256) void agg_all_kernel(
    const unsigned short* __restrict__ xg, const unsigned short* __restrict__ xt,
    const int* __restrict__ off, const int* __restrict__ sorted,
    unsigned short* __restrict__ aggA, unsigned short* __restrict__ aggC,
    unsigned short* __restrict__ aggB)
{
    const int t = threadIdx.x;
    const int node = blockIdx.x * 16 + (t >> 4);
    if (node >= NSEG) return;
    const int l = t & 15;
    const int gb = (t & 63) & ~15;   // group base lane within wave
    const int s0 = off[node];
    const int s1 = off[node + 1];

    const unsigned short* xb;
    unsigned short* out;
    int local, zrow;
    if (node < NG)           { xb = xg; out = aggA; local = node;           zrow = NG; }
    else if (node < NG + NT) { xb = xg; out = aggC; local = node - NG;      zrow = NG; }
    else                     { xb = xt; out = aggB; local = node - NG - NT; zrow = NT; }

    float a0 = 0.f, a1 = 0.f, a2 = 0.f, a3 = 0.f, a4 = 0.f, a5 = 0.f, a6 = 0.f, a7 = 0.f;

    for (int e = s0; e < s1; e += 16) {
        const int cnt = min(s1 - e, 16);
        const int myidx = sorted[e + min(l, cnt - 1)];
#pragma unroll
        for (int j = 0; j < 16; j += 4) {
            if (j < cnt) {
                const int i0 = __shfl(myidx, gb + j, 64);
                const int i1 = (j + 1 < cnt) ? __shfl(myidx, gb + j + 1, 64) : zrow;
                const int i2 = (j + 2 < cnt) ? __shfl(myidx, gb + j + 2, 64) : zrow;
                const int i3 = (j + 3 < cnt) ? __shfl(myidx, gb + j + 3, 64) : zrow;
                const uint4 v0 = *(const uint4*)(xb + (size_t)i0 * D + l * 8);
                const uint4 v1 = *(const uint4*)(xb + (size_t)i1 * D + l * 8);
                const uint4 v2 = *(const uint4*)(xb + (size_t)i2 * D + l * 8);
                const uint4 v3 = *(const uint4*)(xb + (size_t)i3 * D + l * 8);
                a0 += bflo(v0.x) + bflo(v1.x) + bflo(v2.x) + bflo(v3.x);
                a1 += bfhi(v0.x) + bfhi(v1.x) + bfhi(v2.x) + bfhi(v3.x);
                a2 += bflo(v0.y) + bflo(v1.y) + bflo(v2.y) + bflo(v3.y);
                a3 += bfhi(v0.y) + bfhi(v1.y) + bfhi(v2.y) + bfhi(v3.y);
                a4 += bflo(v0.z) + bflo(v1.z) + bflo(v2.z) + bflo(v3.z);
                a5 += bfhi(v0.z) + bfhi(v1.z) + bfhi(v2.z) + bfhi(v3.z);
                a6 += bflo(v0.w) + bflo(v1.w) + bflo(v2.w) + bflo(v3.w);
                a7 += bfhi(v0.w) + bfhi(v1.w) + bfhi(v2.w) + bfhi(v3.w);
            }
        }
    }

    const float inv = 1.0f / (float)max(s1 - s0, 1);
    uint4 o;
    o.x = (unsigned int)f2bf(a0 * inv) | ((unsigned int)f2bf(a1 * inv) << 16);
    o.y = (unsigned int)f2bf(a2 * inv) | ((unsigned int)f2bf(a3 * inv) << 16);
    o.z = (unsigned int)f2bf(a4 * inv) | ((unsigned int)f2bf(a5 * inv) << 16);
    o.w = (unsigned int)f2bf(a6 * inv) | ((unsigned int)f2bf(a7 * inv) << 16);
    *(uint4*)(out + (size_t)local * D + l * 8) = o;
}

// ---------------- MFMA GEMM, both outputs in one launch ----------------
// blocks [0,GB): gene (3 sources); [GB,GB+TB): trait (2 sources).
// 1024 threads = 16 waves; wave = one 32-row tile; operand-swapped mfma(W, x).
__global__ __launch_bounds__(1024) void gemm_all(
    const unsigned short* __restrict__ xbG, const unsigned short* __restrict__ xbT,
    const unsigned short* __restrict__ aggA, const unsigned short* __restrict__ aggB,
    const unsigned short* __restrict__ aggC,
    const unsigned short* __restrict__ WpG, const unsigned short* __restrict__ WpT,
    const float* __restrict__ biasG, const float* __restrict__ biasT,
    float* __restrict__ outG, float* __restrict__ outT, int GB)
{
    __shared__ unsigned short WL[8 * 4 * 64 * 8];   // 32 KiB: one source slice
    const int t = threadIdx.x;
    const int wid = t >> 6, lane = t & 63;
    const int lm = lane & 31, l5 = lane >> 5;

    const bool isG = (int)blockIdx.x < GB;
    const int bloc = isG ? blockIdx.x : blockIdx.x - GB;
    const int M = isG ? NG : NT;
    const int nsrc = isG ? 3 : 2;
    const unsigned short* A0 = isG ? xbG : xbT;
    const unsigned short* A1 = isG ? aggA : aggC;
    const unsigned short* A2 = aggB;
    const unsigned short* Wpack = isG ? WpG : WpT;
    const float* bias = isG ? biasG : biasT;
    float* out = isG ? outG : outT;

    const int tile = bloc * 16 + wid;
    const bool active = tile * 32 < M;
    const int m = tile * 32 + lm;

    f32x16 acc[4];
    if (active) {
#pragma unroll
        for (int nt = 0; nt < 4; ++nt) {
#pragma unroll
            for (int q = 0; q < 4; ++q) {
                const float4 bq = *(const float4*)&bias[nt * 32 + 4 * l5 + 8 * q];
                acc[nt][4 * q + 0] = bq.x; acc[nt][4 * q + 1] = bq.y;
                acc[nt][4 * q + 2] = bq.z; acc[nt][4 * q + 3] = bq.w;
            }
        }
    }

    const uint4* wg = (const uint4*)Wpack;
    uint4* wl = (uint4*)WL;

#pragma unroll 1
    for (int s = 0; s < nsrc; ++s) {
        __syncthreads();
        wl[t]        = wg[(size_t)s * 2048 + t];
        wl[t + 1024] = wg[(size_t)s * 2048 + t + 1024];
        __syncthreads();
        if (!active) continue;
        const unsigned short* ag = (s == 0) ? A0 : ((s == 1) ? A1 : A2);
        const unsigned short* ar = ag + (size_t)m * D + l5 * 8;
#pragma unroll
        for (int kt = 0; kt < 8; ++kt) {
            const bf16x8 a = *(const bf16x8*)(ar + kt * 16);
#pragma unroll
            for (int nt = 0; nt < 4; ++nt) {
                const bf16x8 b = *(const bf16x8*)&WL[((kt * 4 + nt) * 64 + lane) * 8];
                acc[nt] = __builtin_amdgcn_mfma_f32_32x32x16_bf16(b, a, acc[nt], 0, 0, 0);
            }
        }
    }

    if (active) {
        float* orow = out + (size_t)m * D;
#pragma unroll
        for (int nt = 0; nt < 4; ++nt) {
            float* p = orow + nt * 32 + 4 * l5;
            *(float4*)(p + 0)  = make_float4(acc[nt][0],  acc[nt][1],  acc[nt][2],  acc[nt][3]);
            *(float4*)(p + 8)  = make_float4(acc[nt][4],  acc[nt][5],  acc[nt][6],  acc[nt][7]);
            *(float4*)(p + 16) = make_float4(acc[nt][8],  acc[nt][9],  acc[nt][10], acc[nt][11]);
            *(float4*)(p + 24) = make_float4(acc[nt][12], acc[nt][13], acc[nt][14], acc[nt][15]);
        }
    }
}

extern "C" void kernel_launch(void* const* d_in, const int* in_sizes, int n_in,
                              void* d_out, int out_size, void* d_ws, size_t ws_size,
                              hipStream_t stream)
{
    const float* x_gene  = (const float*)d_in[0];
    const float* x_trait = (const float*)d_in[1];
    const int* src_gg = (const int*)d_in[2];
    const int* dst_gg = (const int*)d_in[3];
    const int* src_gt = (const int*)d_in[4];
    const int* dst_gt = (const int*)d_in[5];
    const int* src_tg = (const int*)d_in[6];
    const int* dst_tg = (const int*)d_in[7];
    const float* Wn_gg = (const float*)d_in[8];
    const float* Ws_gg = (const float*)d_in[9];
    const float* b_gg  = (const float*)d_in[10];
    const float* Wn_gt = (const float*)d_in[11];
    const float* Ws_gt = (const float*)d_in[12];
    const float* b_gt  = (const float*)d_in[13];
    const float* Wn_tg = (const float*)d_in[14];
    const float* Ws_tg = (const float*)d_in[15];
    const float* b_tg  = (const float*)d_in[16];

    const int nE_gg = in_sizes[2];
    const int nE_gt = in_sizes[4];
    const int nE_tg = in_sizes[6];
    const int nE_total = nE_gg + nE_gt + nE_tg;

    float* out_gene  = (float*)d_out;
    float* out_trait = (float*)d_out + (size_t)NG * D;

    // ws (~150 MB, no aliasing): xb_gene[(NG+1)*D] | xb_trait[(NT+1)*D] |
    //   aggA[NG*D] | aggB[NG*D] | aggC[NT*D] (bf16) | WpG | WpT | biasG | biasT |
    //   off | bcount | bbase | bcursor | sorted | binned
    unsigned short* xb_gene  = (unsigned short*)d_ws;
    unsigned short* xb_trait = xb_gene + (size_t)(NG + 1) * D;
    unsigned short* aggA = xb_trait + (size_t)(NT + 1) * D;
    unsigned short* aggB = aggA + (size_t)NG * D;
    unsigned short* aggC = aggB + (size_t)NG * D;
    char* p = (char*)(aggC + (size_t)NT * D);
    unsigned short* WpG = (unsigned short*)p;  p += 24 * 4 * 64 * 8 * sizeof(unsigned short);
    unsigned short* WpT = (unsigned short*)p;  p += 16 * 4 * 64 * 8 * sizeof(unsigned short);
    float* biasG = (float*)p;                  p += D * sizeof(float);
    float* biasT = (float*)p;                  p += D * sizeof(float);
    int* off     = (int*)p;                    p += (size_t)(NSEG + 1) * sizeof(int);
    int* bcount  = (int*)p;                    p += NBUCK * sizeof(int);
    int* bbase   = (int*)p;                    p += (NBUCK + 1) * sizeof(int);
    int* bcursor = (int*)p;                    p += NBUCK * sizeof(int);
    int* sorted  = (int*)p;                    p += (size_t)nE_total * sizeof(int);
    int2* binned = (int2*)p;

    // weight pack + bias fold; bf16 feature tables (+zero rows) in one launch
    prep_kernel<<<41, 256, 0, stream>>>(Ws_gg, Ws_tg, Wn_gg, Wn_tg, Ws_gt, Wn_gt,
                                        b_gg, b_tg, b_gt, WpG, WpT, biasG, biasT);
    cvt2_kernel<<<(((NG + 1) + (NT + 1)) * D / 8 + 255) / 256, 256, 0, stream>>>(
        x_gene, x_trait, xb_gene, xb_trait);

    // CSR build via two-phase binning
    const int nWG = (nE_total + TILE - 1) / TILE;
    hipMemsetAsync(bcount, 0, NBUCK * sizeof(int), stream);
    bcount_kernel<<<nWG, 256, 0, stream>>>(dst_gg, nE_gg, dst_gt, nE_gt, dst_tg,
                                           nE_total, bcount);
    bscan_kernel<<<1, 256, 0, stream>>>(bcount, bbase, bcursor, off);
    bscatter_kernel<<<nWG, 256, 0, stream>>>(
        src_gg, dst_gg, nE_gg, src_gt, dst_gt, nE_gt, src_tg, dst_tg,
        nE_total, bcursor, binned);
    bbuild_kernel<<<NBUCK, 256, 0, stream>>>(binned, bbase, off, sorted);

    // fused aggregation over all 300k dst nodes (gg->aggA, gt->aggC, tg->aggB)
    agg_all_kernel<<<(NSEG + 15) / 16, 256, 0, stream>>>(
        xb_gene, xb_trait, off, sorted, aggA, aggC, aggB);

    // both output GEMMs in one launch
    const int GBb = ((NG + 31) / 32 + 15) / 16;   // 196
    const int TBb = ((NT + 31) / 32 + 15) / 16;   // 196
    gemm_all<<<GBb + TBb, 1024, 0, stream>>>(
        xb_gene, xb_trait, aggA, aggB, aggC, WpG, WpT, biasG, biasT,
        out_gene, out_trait, GBb);
}

// Round 11
// 199.412 us; speedup vs baseline: 1.4378x; 1.0239x over previous
//
#include <hip/hip_runtime.h>
#include <hip/hip_bf16.h>

// HeteroGCN: 3x SAGEConv(mean).
// R1-R8: CSR gather (no atomics), two-phase LDS binning CSR build, bf16 MFMA
//        GEMM with K-concat + packed weights, bf16 feature tables.
// R9 (failed): agg-in-GEMM fusion -> 8% occupancy, reverted.
// R10: agg index-broadcast via __shfl; zero-row tail padding; one GEMM launch.
// R11: packed f32 accumulate in agg (v_pk_add_f32, -25% VALU); launch chain
//      9 -> 6 dispatches: setup kernel fuses cvt+weight-pack+counter-zeroing,
//      bscan eliminated (each bscatter/bbuild WG recomputes the 256-bucket
//      base scan locally from bcount; ordering via zero-based delta cursors).

#define D 128
#define NG 100000
#define NT 100000
#define NSEG (NG + NT + NG)   // concatenated dst-node counters: gg | gt | tg

#define NBUCK 256
#define NPB   ((NSEG + NBUCK - 1) / NBUCK)   // 1172 seg-nodes per bucket
#define TILE  4096                            // edges per bscatter workgroup

typedef __bf16 bf16x8 __attribute__((ext_vector_type(8)));
typedef float f32x16 __attribute__((ext_vector_type(16)));
typedef float v2f __attribute__((ext_vector_type(2)));

static __device__ __forceinline__ unsigned short f2bf(float f) {
    return __builtin_bit_cast(unsigned short, (__bf16)f);
}
static __device__ __forceinline__ float bflo(unsigned int v) {
    return __builtin_bit_cast(float, v << 16);
}
static __device__ __forceinline__ float bfhi(unsigned int v) {
    return __builtin_bit_cast(float, v & 0xffff0000u);
}

// ---------------- setup: bf16 tables (+zero row) | weight pack | zero counters ----------------
#define CVT8 (((NG + 1) + (NT + 1)) * D / 8)

__global__ __launch_bounds__(256) void setup_kernel(
    const float* __restrict__ xg, const float* __restrict__ xt,
    unsigned short* __restrict__ og, unsigned short* __restrict__ ot,
    const float* __restrict__ Ws_gg, const float* __restrict__ Ws_tg,
    const float* __restrict__ Wn_gg, const float* __restrict__ Wn_tg,
    const float* __restrict__ Ws_gt, const float* __restrict__ Wn_gt,
    const float* __restrict__ b_gg, const float* __restrict__ b_tg,
    const float* __restrict__ b_gt,
    unsigned short* __restrict__ WpG, unsigned short* __restrict__ WpT,
    float* __restrict__ biasG, float* __restrict__ biasT,
    int* __restrict__ zero512)
{
    const int gid = blockIdx.x * 256 + threadIdx.x;
    if (gid < CVT8) {
        // feature table cvt, zero row appended per table
        const int ng8 = (NG + 1) * D / 8;
        const float* x; unsigned short* o; int j, nreal8;
        if (gid < ng8) { x = xg; o = og; j = gid;       nreal8 = NG * D / 8; }
        else           { x = xt; o = ot; j = gid - ng8; nreal8 = NT * D / 8; }
        uint4 v = make_uint4(0, 0, 0, 0);
        if (j < nreal8) {
            const float4 f0 = ((const float4*)x)[j * 2];
            const float4 f1 = ((const float4*)x)[j * 2 + 1];
            v.x = (unsigned int)f2bf(f0.x) | ((unsigned int)f2bf(f0.y) << 16);
            v.y = (unsigned int)f2bf(f0.z) | ((unsigned int)f2bf(f0.w) << 16);
            v.z = (unsigned int)f2bf(f1.x) | ((unsigned int)f2bf(f1.y) << 16);
            v.w = (unsigned int)f2bf(f1.z) | ((unsigned int)f2bf(f1.w) << 16);
        }
        ((uint4*)o)[j] = v;
        return;
    }
    const int g2 = gid - CVT8;
    if (g2 < 6144) {                        // gene pack: 24 kt * 4 nt * 64 lanes
        const int lane = g2 & 63, nt = (g2 >> 6) & 3, kt = g2 >> 8;
        const int n = nt * 32 + (lane & 31);
        const int kb = kt * 16 + (lane >> 5) * 8;
        unsigned int pk[4];
#pragma unroll
        for (int jj = 0; jj < 4; ++jj) {
            unsigned int w2 = 0;
#pragma unroll
            for (int h = 0; h < 2; ++h) {
                const int k = kb + jj * 2 + h;
                float w;
                if (k < 128)      w = Ws_gg[k * D + n] + Ws_tg[k * D + n];
                else if (k < 256) w = Wn_gg[(k - 128) * D + n];
                else              w = Wn_tg[(k - 256) * D + n];
                w2 |= ((unsigned int)f2bf(w)) << (16 * h);
            }
            pk[jj] = w2;
        }
        *(uint4*)(WpG + (size_t)g2 * 8) = make_uint4(pk[0], pk[1], pk[2], pk[3]);
    } else if (g2 < 6144 + 4096) {          // trait pack: 16 kt * 4 nt * 64 lanes
        const int g = g2 - 6144;
        const int lane = g & 63, nt = (g >> 6) & 3, kt = g >> 8;
        const int n = nt * 32 + (lane & 31);
        const int kb = kt * 16 + (lane >> 5) * 8;
        unsigned int pk[4];
#pragma unroll
        for (int jj = 0; jj < 4; ++jj) {
            unsigned int w2 = 0;
#pragma unroll
            for (int h = 0; h < 2; ++h) {
                const int k = kb + jj * 2 + h;
                const float w = (k < 128) ? Ws_gt[k * D + n] : Wn_gt[(k - 128) * D + n];
                w2 |= ((unsigned int)f2bf(w)) << (16 * h);
            }
            pk[jj] = w2;
        }
        *(uint4*)(WpT + (size_t)g * 8) = make_uint4(pk[0], pk[1], pk[2], pk[3]);
    } else if (g2 < 10240 + 128) {
        const int i = g2 - 10240;
        biasG[i] = b_gg[i] + b_tg[i];
    } else if (g2 < 10368 + 128) {
        const int i = g2 - 10368;
        biasT[i] = b_gt[i];
    } else if (g2 < 10496 + 512) {
        zero512[g2 - 10496] = 0;            // bcount[256] + bcursor[256]
    }
}

// ---------------- binning (CSR build) ----------------
static __device__ __forceinline__ int edge_seg(
    int ge, const int* d0, int n0, const int* d1, int n1, const int* d2)
{
    if (ge < n0) return d0[ge];
    if (ge < n0 + n1) return NG + d1[ge - n0];
    return NG + NT + d2[ge - n0 - n1];
}
static __device__ __forceinline__ int edge_src(
    int ge, const int* s0, int n0, const int* s1, int n1, const int* s2)
{
    if (ge < n0) return s0[ge];
    if (ge < n0 + n1) return s1[ge - n0];
    return s2[ge - n0 - n1];
}

__global__ __launch_bounds__(256) void bcount_kernel(
    const int* __restrict__ d0, int n0, const int* __restrict__ d1, int n1,
    const int* __restrict__ d2, int nE, int* __restrict__ bcount)
{
    __shared__ int hist[NBUCK];
    const int t = threadIdx.x;
    hist[t] = 0;
    __syncthreads();
    const int base = blockIdx.x * TILE;
#pragma unroll
    for (int j = 0; j < TILE / 256; ++j) {
        const int ge = base + j * 256 + t;
        if (ge < nE) {
            const int seg = edge_seg(ge, d0, n0, d1, n1, d2);
            atomicAdd(&hist[seg / NPB], 1);
        }
    }
    __syncthreads();
    if (hist[t]) atomicAdd(&bcount[t], hist[t]);
}

// bscatter: recomputes the 256-bucket exclusive base scan locally from bcount,
// reserves its global slot via zero-based delta cursors, dumps bucket-contiguous.
__global__ __launch_bounds__(256) void bscatter_kernel(
    const int* __restrict__ s0, const int* __restrict__ d0, int n0,
    const int* __restrict__ s1, const int* __restrict__ d1, int n1,
    const int* __restrict__ s2, const int* __restrict__ d2, int nE,
    const int* __restrict__ bcount, int* __restrict__ bcursor,
    int2* __restrict__ binned)
{
    __shared__ int2 stage[TILE];
    __shared__ int hist[NBUCK], scn[NBUCK], gbase[NBUCK], lcur[NBUCK], gb0[NBUCK];
    const int t = threadIdx.x;
    hist[t] = 0;
    // global bucket-base scan (from completed bcount)
    const int gc = bcount[t];
    gb0[t] = gc;
    __syncthreads();
    for (int sh = 1; sh < NBUCK; sh <<= 1) {
        int u = (t >= sh) ? gb0[t - sh] : 0;
        __syncthreads();
        gb0[t] += u;
        __syncthreads();
    }
    const int gexcl = gb0[t] - gc;

    const int base = blockIdx.x * TILE;
    int mseg[TILE / 256], msrc[TILE / 256];
#pragma unroll
    for (int j = 0; j < TILE / 256; ++j) {
        const int ge = base + j * 256 + t;
        if (ge < nE) {
            mseg[j] = edge_seg(ge, d0, n0, d1, n1, d2);
            msrc[j] = edge_src(ge, s0, n0, s1, n1, s2);
            atomicAdd(&hist[mseg[j] / NPB], 1);
        } else mseg[j] = -1;
    }
    __syncthreads();

    const int h = hist[t];
    scn[t] = h;
    __syncthreads();
    for (int sh = 1; sh < NBUCK; sh <<= 1) {
        int u = (t >= sh) ? scn[t - sh] : 0;
        __syncthreads();
        scn[t] += u;
        __syncthreads();
    }
    const int excl = scn[t] - h;
    __syncthreads();
    scn[t] = excl;
    lcur[t] = excl;
    if (h) gbase[t] = gexcl + atomicAdd(&bcursor[t], h);
    __syncthreads();

#pragma unroll
    for (int j = 0; j < TILE / 256; ++j) {
        if (mseg[j] >= 0) {
            const int b = mseg[j] / NPB;
            const int pos = atomicAdd(&lcur[b], 1);
            stage[pos] = make_int2(msrc[j], mseg[j]);
        }
    }
    __syncthreads();

    const int cnt = min(TILE, nE - base);
    for (int slot = t; slot < cnt; slot += 256) {
        const int2 pr = stage[slot];
        const int b = pr.y / NPB;
        binned[gbase[b] + (slot - scn[b])] = pr;
    }
}

// bbuild: per-bucket counting sort in LDS; bucket base recomputed locally.
__global__ __launch_bounds__(256) void bbuild_kernel(
    const int2* __restrict__ binned, const int* __restrict__ bcount,
    int* __restrict__ off, int* __restrict__ sorted)
{
    constexpr int CH = (NPB + 255) / 256;   // 5
    __shared__ int ldeg[NPB];
    __shared__ int loff[NPB];
    __shared__ int psum[256];
    __shared__ int gb0[NBUCK];
    const int t = threadIdx.x;
    const int b = blockIdx.x;

    // bucket base scan from bcount
    const int gc = bcount[t];
    gb0[t] = gc;
    __syncthreads();
    for (int sh = 1; sh < NBUCK; sh <<= 1) {
        int u = (t >= sh) ? gb0[t - sh] : 0;
        __syncthreads();
        gb0[t] += u;
        __syncthreads();
    }
    const int ebase = gb0[b] - bcount[b];
    const int ecnt  = bcount[b];

    const int n0 = b * NPB;
    const int NL = min(NSEG - n0, NPB);

    for (int i = t; i < NL; i += 256) ldeg[i] = 0;
    __syncthreads();
    for (int e = t; e < ecnt; e += 256)
        atomicAdd(&ldeg[binned[ebase + e].y - n0], 1);
    __syncthreads();

    int s = 0;
#pragma unroll
    for (int k = 0; k < CH; ++k) {
        const int i = t * CH + k;
        if (i < NL) s += ldeg[i];
    }
    psum[t] = s;
    __syncthreads();
    for (int sh = 1; sh < 256; sh <<= 1) {
        int u = (t >= sh) ? psum[t - sh] : 0;
        __syncthreads();
        psum[t] += u;
        __syncthreads();
    }
    int run = psum[t] - s;
#pragma unroll
    for (int k = 0; k < CH; ++k) {
        const int i = t * CH + k;
        if (i < NL) { loff[i] = run; run += ldeg[i]; }
    }
    __syncthreads();

    for (int i = t; i < NL; i += 256) off[n0 + i] = ebase + loff[i];
    if (b == NBUCK - 1 && t == 0) off[NSEG] = ebase + ecnt;
    __syncthreads();

    for (int e = t; e < ecnt; e += 256) {
        const int2 pr = binned[ebase + e];
        const int slot = atomicAdd(&loff[pr.y - n0], 1);
        sorted[ebase + slot] = pr.x;
    }
}

// ---------------- aggregation: idx-broadcast gather, packed f32 accumulate ----------------
// 256 threads = 16 nodes/block; 16-lane group per node, lane covers 8 cols.
// Per 16-edge batch: ONE coalesced index load + __shfl broadcast; tail lanes
// read the zero row (L1-hot). Accumulators are float2 -> v_pk_add_f32.
__global__ __launch_bounds__(256) void agg_all_kernel(
    const unsigned short* __restrict__ xg, const unsigned short* __restrict__ xt,
    const int* __restrict__ off, const int* __restrict__ sorted,
    unsigned short* __restrict__ aggA, unsigned short* __restrict__ aggC,
    unsigned short* __restrict__ aggB)
{
    const int t = threadIdx.x;
    const int node = blockIdx.x * 16 + (t >> 4);
    if (node >= NSEG) return;
    const int l = t & 15;
    const int gb = (t & 63) & ~15;   // group base lane within wave
    const int s0 = off[node];
    const int s1 = off[node + 1];

    const unsigned short* xb;
    unsigned short* out;
    int local, zrow;
    if (node < NG)           { xb = xg; out = aggA; local = node;           zrow = NG; }
    else if (node < NG + NT) { xb = xg; out = aggC; local = node - NG;      zrow = NG; }
    else                     { xb = xt; out = aggB; local = node - NG - NT; zrow = NT; }

    v2f A0 = (v2f){0.f, 0.f}, A1 = (v2f){0.f, 0.f};
    v2f A2 = (v2f){0.f, 0.f}, A3 = (v2f){0.f, 0.f};

    for (int e = s0; e < s1; e += 16) {
        const int cnt = min(s1 - e, 16);
        const int myidx = sorted[e + min(l, cnt - 1)];
#pragma unroll
        for (int j = 0; j < 16; j += 4) {
            if (j < cnt) {
                const int i0 = __shfl(myidx, gb + j, 64);
                const int i1 = (j + 1 < cnt) ? __shfl(myidx, gb + j + 1, 64) : zrow;
                const int i2 = (j + 2 < cnt) ? __shfl(myidx, gb + j + 2, 64) : zrow;
                const int i3 = (j + 3 < cnt) ? __shfl(myidx, gb + j + 3, 64) : zrow;
                const uint4 v0 = *(const uint4*)(xb + (size_t)i0 * D + l * 8);
                const uint4 v1 = *(const uint4*)(xb + (size_t)i1 * D + l * 8);
                const uint4 v2 = *(const uint4*)(xb + (size_t)i2 * D + l * 8);
                const uint4 v3 = *(const uint4*)(xb + (size_t)i3 * D + l * 8);
                A0 += (v2f){bflo(v0.x), bfhi(v0.x)};
                A1 += (v2f){bflo(v0.y), bfhi(v0.y)};
                A2 += (v2f){bflo(v0.z), bfhi(v0.z)};
                A3 += (v2f){bflo(v0.w), bfhi(v0.w)};
                A0 += (v2f){bflo(v1.x), bfhi(v1.x)};
                A1 += (v2f){bflo(v1.y), bfhi(v1.y)};
                A2 += (v2f){bflo(v1.z), bfhi(v1.z)};
                A3 += (v2f){bflo(v1.w), bfhi(v1.w)};
                A0 += (v2f){bflo(v2.x), bfhi(v2.x)};
                A1 += (v2f){bflo(v2.y), bfhi(v2.y)};
                A2 += (v2f){bflo(v2.z), bfhi(v2.z)};
                A3 += (v2f){bflo(v2.w), bfhi(v2.w)};
                A0 += (v2f){bflo(v3.x), bfhi(v3.x)};
                A1 += (v2f){bflo(v3.y), bfhi(v3.y)};
                A2 += (v2f){bflo(v3.z), bfhi(v3.z)};
                A3 += (v2f){bflo(v3.w), bfhi(v3.w)};
            }
        }
    }

    const float inv = 1.0f / (float)max(s1 - s0, 1);
    uint4 o;
    o.x = (unsigned int)f2bf(A0.x * inv) | ((unsigned int)f2bf(A0.y * inv) << 16);
    o.y = (unsigned int)f2bf(A1.x * inv) | ((unsigned int)f2bf(A1.y * inv) << 16);
    o.z = (unsigned int)f2bf(A2.x * inv) | ((unsigned int)f2bf(A2.y * inv) << 16);
    o.w = (unsigned int)f2bf(A3.x * inv) | ((unsigned int)f2bf(A3.y * inv) << 16);
    *(uint4*)(out + (size_t)local * D + l * 8) = o;
}

// ---------------- MFMA GEMM, both outputs in one launch ----------------
__global__ __launch_bounds__(1024) void gemm_all(
    const unsigned short* __restrict__ xbG, const unsigned short* __restrict__ xbT,
    const unsigned short* __restrict__ aggA, const unsigned short* __restrict__ aggB,
    const unsigned short* __restrict__ aggC,
    const unsigned short* __restrict__ WpG, const unsigned short* __restrict__ WpT,
    const float* __restrict__ biasG, const float* __restrict__ biasT,
    float* __restrict__ outG, float* __restrict__ outT, int GB)
{
    __shared__ unsigned short WL[8 * 4 * 64 * 8];   // 32 KiB: one source slice
    const int t = threadIdx.x;
    const int wid = t >> 6, lane = t & 63;
    const int lm = lane & 31, l5 = lane >> 5;

    const bool isG = (int)blockIdx.x < GB;
    const int bloc = isG ? blockIdx.x : blockIdx.x - GB;
    const int M = isG ? NG : NT;
    const int nsrc = isG ? 3 : 2;
    const unsigned short* A0 = isG ? xbG : xbT;
    const unsigned short* A1 = isG ? aggA : aggC;
    const unsigned short* A2 = aggB;
    const unsigned short* Wpack = isG ? WpG : WpT;
    const float* bias = isG ? biasG : biasT;
    float* out = isG ? outG : outT;

    const int tile = bloc * 16 + wid;
    const bool active = tile * 32 < M;
    const int m = tile * 32 + lm;

    f32x16 acc[4];
    if (active) {
#pragma unroll
        for (int nt = 0; nt < 4; ++nt) {
#pragma unroll
            for (int q = 0; q < 4; ++q) {
                const float4 bq = *(const float4*)&bias[nt * 32 + 4 * l5 + 8 * q];
                acc[nt][4 * q + 0] = bq.x; acc[nt][4 * q + 1] = bq.y;
                acc[nt][4 * q + 2] = bq.z; acc[nt][4 * q + 3] = bq.w;
            }
        }
    }

    const uint4* wg = (const uint4*)Wpack;
    uint4* wl = (uint4*)WL;

#pragma unroll 1
    for (int s = 0; s < nsrc; ++s) {
        __syncthreads();
        wl[t]        = wg[(size_t)s * 2048 + t];
        wl[t + 1024] = wg[(size_t)s * 2048 + t + 1024];
        __syncthreads();
        if (!active) continue;
        const unsigned short* ag = (s == 0) ? A0 : ((s == 1) ? A1 : A2);
        const unsigned short* ar = ag + (size_t)m * D + l5 * 8;
#pragma unroll
        for (int kt = 0; kt < 8; ++kt) {
            const bf16x8 a = *(const bf16x8*)(ar + kt * 16);
#pragma unroll
            for (int nt = 0; nt < 4; ++nt) {
                const bf16x8 b = *(const bf16x8*)&WL[((kt * 4 + nt) * 64 + lane) * 8];
                acc[nt] = __builtin_amdgcn_mfma_f32_32x32x16_bf16(b, a, acc[nt], 0, 0, 0);
            }
        }
    }

    if (active) {
        float* orow = out + (size_t)m * D;
#pragma unroll
        for (int nt = 0; nt < 4; ++nt) {
            float* p = orow + nt * 32 + 4 * l5;
            *(float4*)(p + 0)  = make_float4(acc[nt][0],  acc[nt][1],  acc[nt][2],  acc[nt][3]);
            *(float4*)(p + 8)  = make_float4(acc[nt][4],  acc[nt][5],  acc[nt][6],  acc[nt][7]);
            *(float4*)(p + 16) = make_float4(acc[nt][8],  acc[nt][9],  acc[nt][10], acc[nt][11]);
            *(float4*)(p + 24) = make_float4(acc[nt][12], acc[nt][13], acc[nt][14], acc[nt][15]);
        }
    }
}

extern "C" void kernel_launch(void* const* d_in, const int* in_sizes, int n_in,
                              void* d_out, int out_size, void* d_ws, size_t ws_size,
                              hipStream_t stream)
{
    const float* x_gene  = (const float*)d_in[0];
    const float* x_trait = (const float*)d_in[1];
    const int* src_gg = (const int*)d_in[2];
    const int* dst_gg = (const int*)d_in[3];
    const int* src_gt = (const int*)d_in[4];
    const int* dst_gt = (const int*)d_in[5];
    const int* src_tg = (const int*)d_in[6];
    const int* dst_tg = (const int*)d_in[7];
    const float* Wn_gg = (const float*)d_in[8];
    const float* Ws_gg = (const float*)d_in[9];
    const float* b_gg  = (const float*)d_in[10];
    const float* Wn_gt = (const float*)d_in[11];
    const float* Ws_gt = (const float*)d_in[12];
    const float* b_gt  = (const float*)d_in[13];
    const float* Wn_tg = (const float*)d_in[14];
    const float* Ws_tg = (const float*)d_in[15];
    const float* b_tg  = (const float*)d_in[16];

    const int nE_gg = in_sizes[2];
    const int nE_gt = in_sizes[4];
    const int nE_tg = in_sizes[6];
    const int nE_total = nE_gg + nE_gt + nE_tg;

    float* out_gene  = (float*)d_out;
    float* out_trait = (float*)d_out + (size_t)NG * D;

    // ws (~150 MB): xb_gene[(NG+1)*D] | xb_trait[(NT+1)*D] | aggA | aggB | aggC |
    //   WpG | WpT | biasG | biasT | off | bcount[256]+bcursor[256] | sorted | binned
    unsigned short* xb_gene  = (unsigned short*)d_ws;
    unsigned short* xb_trait = xb_gene + (size_t)(NG + 1) * D;
    unsigned short* aggA = xb_trait + (size_t)(NT + 1) * D;
    unsigned short* aggB = aggA + (size_t)NG * D;
    unsigned short* aggC = aggB + (size_t)NG * D;
    char* p = (char*)(aggC + (size_t)NT * D);
    unsigned short* WpG = (unsigned short*)p;  p += 24 * 4 * 64 * 8 * sizeof(unsigned short);
    unsigned short* WpT = (unsigned short*)p;  p += 16 * 4 * 64 * 8 * sizeof(unsigned short);
    float* biasG = (float*)p;                  p += D * sizeof(float);
    float* biasT = (float*)p;                  p += D * sizeof(float);
    int* off     = (int*)p;                    p += (size_t)(NSEG + 1) * sizeof(int);
    int* bcount  = (int*)p;                    p += NBUCK * sizeof(int);
    int* bcursor = (int*)p;                    p += NBUCK * sizeof(int);
    int* sorted  = (int*)p;                    p += (size_t)nE_total * sizeof(int);
    int2* binned = (int2*)p;

    // 1) setup: feature tables + weight pack + zero bcount/bcursor
    const int setup_blocks = (CVT8 + 10496 + 512 + 255) / 256;
    setup_kernel<<<setup_blocks, 256, 0, stream>>>(
        x_gene, x_trait, xb_gene, xb_trait,
        Ws_gg, Ws_tg, Wn_gg, Wn_tg, Ws_gt, Wn_gt, b_gg, b_tg, b_gt,
        WpG, WpT, biasG, biasT, bcount);

    // 2) CSR build via two-phase binning (bscan folded into bscatter/bbuild)
    const int nWG = (nE_total + TILE - 1) / TILE;
    bcount_kernel<<<nWG, 256, 0, stream>>>(dst_gg, nE_gg, dst_gt, nE_gt, dst_tg,
                                           nE_total, bcount);
    bscatter_kernel<<<nWG, 256, 0, stream>>>(
        src_gg, dst_gg, nE_gg, src_gt, dst_gt, nE_gt, src_tg, dst_tg,
        nE_total, bcount, bcursor, binned);
    bbuild_kernel<<<NBUCK, 256, 0, stream>>>(binned, bcount, off, sorted);

    // 3) fused aggregation over all 300k dst nodes (gg->aggA, gt->aggC, tg->aggB)
    agg_all_kernel<<<(NSEG + 15) / 16, 256, 0, stream>>>(
        xb_gene, xb_trait, off, sorted, aggA, aggC, aggB);

    // 4) both output GEMMs in one launch
    const int GBb = ((NG + 31) / 32 + 15) / 16;   // 196
    const int TBb = ((NT + 31) / 32 + 15) / 16;   // 196
    gemm_all<<<GBb + TBb, 1024, 0, stream>>>(
        xb_gene, xb_trait, aggA, aggB, aggC, WpG, WpT, biasG, biasT,
        out_gene, out_trait, GBb);
}

// Round 12
// 184.883 us; speedup vs baseline: 1.5508x; 1.0786x over previous
//
#include <hip/hip_runtime.h>
#include <hip/hip_bf16.h>

// HeteroGCN: 3x SAGEConv(mean).
// R1-R8: CSR gather (no atomics), LDS-binning CSR build, bf16 MFMA GEMM with
//        K-concat + packed weights, bf16 feature tables.
// R9 (failed): agg-in-GEMM fusion -> 8% occupancy, reverted.
// R10: agg index-broadcast via __shfl; zero-row tail padding; one GEMM launch.
// R11: setup fuses cvt+weight-pack+counter-zeroing; bscan folded away.
// R12: FIXED-CAPACITY buckets (CAP=8192 >> mean 5860 + 30 sigma): bucket base
//      is b*CAP, so bcount kernel AND both 256-wide bucket-base scans are
//      deleted. off[]/dend[] are bucket-strided start/end per node.

#define D 128
#define NG 100000
#define NT 100000
#define NSEG (NG + NT + NG)   // concatenated dst-node counters: gg | gt | tg

#define NBUCK 256
#define NPB   ((NSEG + NBUCK - 1) / NBUCK)   // 1172 seg-nodes per bucket
#define TILE  4096                            // edges per bscatter workgroup
#define CAP   8192                            // max edges per bucket (mean 5860)

typedef __bf16 bf16x8 __attribute__((ext_vector_type(8)));
typedef float f32x16 __attribute__((ext_vector_type(16)));
typedef float v2f __attribute__((ext_vector_type(2)));

static __device__ __forceinline__ unsigned short f2bf(float f) {
    return __builtin_bit_cast(unsigned short, (__bf16)f);
}
static __device__ __forceinline__ float bflo(unsigned int v) {
    return __builtin_bit_cast(float, v << 16);
}
static __device__ __forceinline__ float bfhi(unsigned int v) {
    return __builtin_bit_cast(float, v & 0xffff0000u);
}

// ---------------- setup: bf16 tables (+zero row) | weight pack | zero cursors ----------------
#define CVT8 (((NG + 1) + (NT + 1)) * D / 8)

__global__ __launch_bounds__(256) void setup_kernel(
    const float* __restrict__ xg, const float* __restrict__ xt,
    unsigned short* __restrict__ og, unsigned short* __restrict__ ot,
    const float* __restrict__ Ws_gg, const float* __restrict__ Ws_tg,
    const float* __restrict__ Wn_gg, const float* __restrict__ Wn_tg,
    const float* __restrict__ Ws_gt, const float* __restrict__ Wn_gt,
    const float* __restrict__ b_gg, const float* __restrict__ b_tg,
    const float* __restrict__ b_gt,
    unsigned short* __restrict__ WpG, unsigned short* __restrict__ WpT,
    float* __restrict__ biasG, float* __restrict__ biasT,
    int* __restrict__ bcursor)
{
    const int gid = blockIdx.x * 256 + threadIdx.x;
    if (gid < CVT8) {
        const int ng8 = (NG + 1) * D / 8;
        const float* x; unsigned short* o; int j, nreal8;
        if (gid < ng8) { x = xg; o = og; j = gid;       nreal8 = NG * D / 8; }
        else           { x = xt; o = ot; j = gid - ng8; nreal8 = NT * D / 8; }
        uint4 v = make_uint4(0, 0, 0, 0);
        if (j < nreal8) {
            const float4 f0 = ((const float4*)x)[j * 2];
            const float4 f1 = ((const float4*)x)[j * 2 + 1];
            v.x = (unsigned int)f2bf(f0.x) | ((unsigned int)f2bf(f0.y) << 16);
            v.y = (unsigned int)f2bf(f0.z) | ((unsigned int)f2bf(f0.w) << 16);
            v.z = (unsigned int)f2bf(f1.x) | ((unsigned int)f2bf(f1.y) << 16);
            v.w = (unsigned int)f2bf(f1.z) | ((unsigned int)f2bf(f1.w) << 16);
        }
        ((uint4*)o)[j] = v;
        return;
    }
    const int g2 = gid - CVT8;
    if (g2 < 6144) {                        // gene pack: 24 kt * 4 nt * 64 lanes
        const int lane = g2 & 63, nt = (g2 >> 6) & 3, kt = g2 >> 8;
        const int n = nt * 32 + (lane & 31);
        const int kb = kt * 16 + (lane >> 5) * 8;
        unsigned int pk[4];
#pragma unroll
        for (int jj = 0; jj < 4; ++jj) {
            unsigned int w2 = 0;
#pragma unroll
            for (int h = 0; h < 2; ++h) {
                const int k = kb + jj * 2 + h;
                float w;
                if (k < 128)      w = Ws_gg[k * D + n] + Ws_tg[k * D + n];
                else if (k < 256) w = Wn_gg[(k - 128) * D + n];
                else              w = Wn_tg[(k - 256) * D + n];
                w2 |= ((unsigned int)f2bf(w)) << (16 * h);
            }
            pk[jj] = w2;
        }
        *(uint4*)(WpG + (size_t)g2 * 8) = make_uint4(pk[0], pk[1], pk[2], pk[3]);
    } else if (g2 < 6144 + 4096) {          // trait pack: 16 kt * 4 nt * 64 lanes
        const int g = g2 - 6144;
        const int lane = g & 63, nt = (g >> 6) & 3, kt = g >> 8;
        const int n = nt * 32 + (lane & 31);
        const int kb = kt * 16 + (lane >> 5) * 8;
        unsigned int pk[4];
#pragma unroll
        for (int jj = 0; jj < 4; ++jj) {
            unsigned int w2 = 0;
#pragma unroll
            for (int h = 0; h < 2; ++h) {
                const int k = kb + jj * 2 + h;
                const float w = (k < 128) ? Ws_gt[k * D + n] : Wn_gt[(k - 128) * D + n];
                w2 |= ((unsigned int)f2bf(w)) << (16 * h);
            }
            pk[jj] = w2;
        }
        *(uint4*)(WpT + (size_t)g * 8) = make_uint4(pk[0], pk[1], pk[2], pk[3]);
    } else if (g2 < 10240 + 128) {
        const int i = g2 - 10240;
        biasG[i] = b_gg[i] + b_tg[i];
    } else if (g2 < 10368 + 128) {
        const int i = g2 - 10368;
        biasT[i] = b_gt[i];
    } else if (g2 < 10496 + NBUCK) {
        bcursor[g2 - 10496] = 0;
    }
}

// ---------------- binning (CSR build, fixed-capacity buckets) ----------------
static __device__ __forceinline__ int edge_seg(
    int ge, const int* d0, int n0, const int* d1, int n1, const int* d2)
{
    if (ge < n0) return d0[ge];
    if (ge < n0 + n1) return NG + d1[ge - n0];
    return NG + NT + d2[ge - n0 - n1];
}
static __device__ __forceinline__ int edge_src(
    int ge, const int* s0, int n0, const int* s1, int n1, const int* s2)
{
    if (ge < n0) return s0[ge];
    if (ge < n0 + n1) return s1[ge - n0];
    return s2[ge - n0 - n1];
}

// bscatter: LDS multi-split; bucket base = b*CAP (no scan, no pre-count).
__global__ __launch_bounds__(256) void bscatter_kernel(
    const int* __restrict__ s0, const int* __restrict__ d0, int n0,
    const int* __restrict__ s1, const int* __restrict__ d1, int n1,
    const int* __restrict__ s2, const int* __restrict__ d2, int nE,
    int* __restrict__ bcursor, int2* __restrict__ binned)
{
    __shared__ int2 stage[TILE];
    __shared__ int hist[NBUCK], scn[NBUCK], gbase[NBUCK], lcur[NBUCK];
    const int t = threadIdx.x;
    hist[t] = 0;
    __syncthreads();

    const int base = blockIdx.x * TILE;
    int mseg[TILE / 256], msrc[TILE / 256];
#pragma unroll
    for (int j = 0; j < TILE / 256; ++j) {
        const int ge = base + j * 256 + t;
        if (ge < nE) {
            mseg[j] = edge_seg(ge, d0, n0, d1, n1, d2);
            msrc[j] = edge_src(ge, s0, n0, s1, n1, s2);
            atomicAdd(&hist[mseg[j] / NPB], 1);
        } else mseg[j] = -1;
    }
    __syncthreads();

    // exclusive scan of the per-WG histogram (for the LDS reorder only)
    const int h = hist[t];
    scn[t] = h;
    __syncthreads();
    for (int sh = 1; sh < NBUCK; sh <<= 1) {
        int u = (t >= sh) ? scn[t - sh] : 0;
        __syncthreads();
        scn[t] += u;
        __syncthreads();
    }
    const int excl = scn[t] - h;
    __syncthreads();
    scn[t] = excl;
    lcur[t] = excl;
    if (h) gbase[t] = t * CAP + atomicAdd(&bcursor[t], h);
    __syncthreads();

#pragma unroll
    for (int j = 0; j < TILE / 256; ++j) {
        if (mseg[j] >= 0) {
            const int b = mseg[j] / NPB;
            const int pos = atomicAdd(&lcur[b], 1);
            stage[pos] = make_int2(msrc[j], mseg[j]);
        }
    }
    __syncthreads();

    const int cnt = min(TILE, nE - base);
    for (int slot = t; slot < cnt; slot += 256) {
        const int2 pr = stage[slot];
        const int b = pr.y / NPB;
        const int gpos = gbase[b] + (slot - scn[b]);
        if (gpos < (b + 1) * CAP)   // defensive: never cross bucket boundary
            binned[gpos] = pr;
    }
}

// bbuild: per-bucket counting sort in LDS; base = b*CAP, count from bcursor.
__global__ __launch_bounds__(256) void bbuild_kernel(
    const int2* __restrict__ binned, const int* __restrict__ bcursor,
    int* __restrict__ off, int* __restrict__ dend, int* __restrict__ sorted)
{
    constexpr int CH = (NPB + 255) / 256;   // 5
    __shared__ int ldeg[NPB];
    __shared__ int loff[NPB];
    __shared__ int psum[256];
    const int t = threadIdx.x;
    const int b = blockIdx.x;
    const int ebase = b * CAP;
    const int ecnt = min(bcursor[b], CAP);

    const int n0 = b * NPB;
    const int NL = min(NSEG - n0, NPB);

    for (int i = t; i < NL; i += 256) ldeg[i] = 0;
    __syncthreads();
    for (int e = t; e < ecnt; e += 256)
        atomicAdd(&ldeg[binned[ebase + e].y - n0], 1);
    __syncthreads();

    int s = 0;
#pragma unroll
    for (int k = 0; k < CH; ++k) {
        const int i = t * CH + k;
        if (i < NL) s += ldeg[i];
    }
    psum[t] = s;
    __syncthreads();
    for (int sh = 1; sh < 256; sh <<= 1) {
        int u = (t >= sh) ? psum[t - sh] : 0;
        __syncthreads();
        psum[t] += u;
        __syncthreads();
    }
    int run = psum[t] - s;
#pragma unroll
    for (int k = 0; k < CH; ++k) {
        const int i = t * CH + k;
        if (i < NL) { loff[i] = run; run += ldeg[i]; }
    }
    __syncthreads();

    for (int i = t; i < NL; i += 256) {
        off[n0 + i]  = ebase + loff[i];
        dend[n0 + i] = ebase + loff[i] + ldeg[i];
    }
    __syncthreads();

    for (int e = t; e < ecnt; e += 256) {
        const int2 pr = binned[ebase + e];
        const int slot = atomicAdd(&loff[pr.y - n0], 1);
        sorted[ebase + slot] = pr.x;
    }
}

// ---------------- aggregation: idx-broadcast gather, packed f32 accumulate ----------------
__global__ __launch_bounds__(256) void agg_all_kernel(
    const unsigned short* __restrict__ xg, const unsigned short* __restrict__ xt,
    const int* __restrict__ off, const int* __restrict__ dend,
    const int* __restrict__ sorted,
    unsigned short* __restrict__ aggA, unsigned short* __restrict__ aggC,
    unsigned short* __restrict__ aggB)
{
    const int t = threadIdx.x;
    const int node = blockIdx.x * 16 + (t >> 4);
    if (node >= NSEG) return;
    const int l = t & 15;
    const int gb = (t & 63) & ~15;   // group base lane within wave
    const int s0 = off[node];
    const int s1 = dend[node];

    const unsigned short* xb;
    unsigned short* out;
    int local, zrow;
    if (node < NG)           { xb = xg; out = aggA; local = node;           zrow = NG; }
    else if (node < NG + NT) { xb = xg; out = aggC; local = node - NG;      zrow = NG; }
    else                     { xb = xt; out = aggB; local = node - NG - NT; zrow = NT; }

    v2f A0 = (v2f){0.f, 0.f}, A1 = (v2f){0.f, 0.f};
    v2f A2 = (v2f){0.f, 0.f}, A3 = (v2f){0.f, 0.f};

    for (int e = s0; e < s1; e += 16) {
        const int cnt = min(s1 - e, 16);
        const int myidx = sorted[e + min(l, cnt - 1)];
#pragma unroll
        for (int j = 0; j < 16; j += 4) {
            if (j < cnt) {
                const int i0 = __shfl(myidx, gb + j, 64);
                const int i1 = (j + 1 < cnt) ? __shfl(myidx, gb + j + 1, 64) : zrow;
                const int i2 = (j + 2 < cnt) ? __shfl(myidx, gb + j + 2, 64) : zrow;
                const int i3 = (j + 3 < cnt) ? __shfl(myidx, gb + j + 3, 64) : zrow;
                const uint4 v0 = *(const uint4*)(xb + (size_t)i0 * D + l * 8);
                const uint4 v1 = *(const uint4*)(xb + (size_t)i1 * D + l * 8);
                const uint4 v2 = *(const uint4*)(xb + (size_t)i2 * D + l * 8);
                const uint4 v3 = *(const uint4*)(xb + (size_t)i3 * D + l * 8);
                A0 += (v2f){bflo(v0.x), bfhi(v0.x)};
                A1 += (v2f){bflo(v0.y), bfhi(v0.y)};
                A2 += (v2f){bflo(v0.z), bfhi(v0.z)};
                A3 += (v2f){bflo(v0.w), bfhi(v0.w)};
                A0 += (v2f){bflo(v1.x), bfhi(v1.x)};
                A1 += (v2f){bflo(v1.y), bfhi(v1.y)};
                A2 += (v2f){bflo(v1.z), bfhi(v1.z)};
                A3 += (v2f){bflo(v1.w), bfhi(v1.w)};
                A0 += (v2f){bflo(v2.x), bfhi(v2.x)};
                A1 += (v2f){bflo(v2.y), bfhi(v2.y)};
                A2 += (v2f){bflo(v2.z), bfhi(v2.z)};
                A3 += (v2f){bflo(v2.w), bfhi(v2.w)};
                A0 += (v2f){bflo(v3.x), bfhi(v3.x)};
                A1 += (v2f){bflo(v3.y), bfhi(v3.y)};
                A2 += (v2f){bflo(v3.z), bfhi(v3.z)};
                A3 += (v2f){bflo(v3.w), bfhi(v3.w)};
            }
        }
    }

    const float inv = 1.0f / (float)max(s1 - s0, 1);
    uint4 o;
    o.x = (unsigned int)f2bf(A0.x * inv) | ((unsigned int)f2bf(A0.y * inv) << 16);
    o.y = (unsigned int)f2bf(A1.x * inv) | ((unsigned int)f2bf(A1.y * inv) << 16);
    o.z = (unsigned int)f2bf(A2.x * inv) | ((unsigned int)f2bf(A2.y * inv) << 16);
    o.w = (unsigned int)f2bf(A3.x * inv) | ((unsigned int)f2bf(A3.y * inv) << 16);
    *(uint4*)(out + (size_t)local * D + l * 8) = o;
}

// ---------------- MFMA GEMM, both outputs in one launch ----------------
__global__ __launch_bounds__(1024) void gemm_all(
    const unsigned short* __restrict__ xbG, const unsigned short* __restrict__ xbT,
    const unsigned short* __restrict__ aggA, const unsigned short* __restrict__ aggB,
    const unsigned short* __restrict__ aggC,
    const unsigned short* __restrict__ WpG, const unsigned short* __restrict__ WpT,
    const float* __restrict__ biasG, const float* __restrict__ biasT,
    float* __restrict__ outG, float* __restrict__ outT, int GB)
{
    __shared__ unsigned short WL[8 * 4 * 64 * 8];   // 32 KiB: one source slice
    const int t = threadIdx.x;
    const int wid = t >> 6, lane = t & 63;
    const int lm = lane & 31, l5 = lane >> 5;

    const bool isG = (int)blockIdx.x < GB;
    const int bloc = isG ? blockIdx.x : blockIdx.x - GB;
    const int M = isG ? NG : NT;
    const int nsrc = isG ? 3 : 2;
    const unsigned short* A0 = isG ? xbG : xbT;
    const unsigned short* A1 = isG ? aggA : aggC;
    const unsigned short* A2 = aggB;
    const unsigned short* Wpack = isG ? WpG : WpT;
    const float* bias = isG ? biasG : biasT;
    float* out = isG ? outG : outT;

    const int tile = bloc * 16 + wid;
    const bool active = tile * 32 < M;
    const int m = tile * 32 + lm;

    f32x16 acc[4];
    if (active) {
#pragma unroll
        for (int nt = 0; nt < 4; ++nt) {
#pragma unroll
            for (int q = 0; q < 4; ++q) {
                const float4 bq = *(const float4*)&bias[nt * 32 + 4 * l5 + 8 * q];
                acc[nt][4 * q + 0] = bq.x; acc[nt][4 * q + 1] = bq.y;
                acc[nt][4 * q + 2] = bq.z; acc[nt][4 * q + 3] = bq.w;
            }
        }
    }

    const uint4* wg = (const uint4*)Wpack;
    uint4* wl = (uint4*)WL;

#pragma unroll 1
    for (int s = 0; s < nsrc; ++s) {
        __syncthreads();
        wl[t]        = wg[(size_t)s * 2048 + t];
        wl[t + 1024] = wg[(size_t)s * 2048 + t + 1024];
        __syncthreads();
        if (!active) continue;
        const unsigned short* ag = (s == 0) ? A0 : ((s == 1) ? A1 : A2);
        const unsigned short* ar = ag + (size_t)m * D + l5 * 8;
#pragma unroll
        for (int kt = 0; kt < 8; ++kt) {
            const bf16x8 a = *(const bf16x8*)(ar + kt * 16);
#pragma unroll
            for (int nt = 0; nt < 4; ++nt) {
                const bf16x8 b = *(const bf16x8*)&WL[((kt * 4 + nt) * 64 + lane) * 8];
                acc[nt] = __builtin_amdgcn_mfma_f32_32x32x16_bf16(b, a, acc[nt], 0, 0, 0);
            }
        }
    }

    if (active) {
        float* orow = out + (size_t)m * D;
#pragma unroll
        for (int nt = 0; nt < 4; ++nt) {
            float* p = orow + nt * 32 + 4 * l5;
            *(float4*)(p + 0)  = make_float4(acc[nt][0],  acc[nt][1],  acc[nt][2],  acc[nt][3]);
            *(float4*)(p + 8)  = make_float4(acc[nt][4],  acc[nt][5],  acc[nt][6],  acc[nt][7]);
            *(float4*)(p + 16) = make_float4(acc[nt][8],  acc[nt][9],  acc[nt][10], acc[nt][11]);
            *(float4*)(p + 24) = make_float4(acc[nt][12], acc[nt][13], acc[nt][14], acc[nt][15]);
        }
    }
}

extern "C" void kernel_launch(void* const* d_in, const int* in_sizes, int n_in,
                              void* d_out, int out_size, void* d_ws, size_t ws_size,
                              hipStream_t stream)
{
    const float* x_gene  = (const float*)d_in[0];
    const float* x_trait = (const float*)d_in[1];
    const int* src_gg = (const int*)d_in[2];
    const int* dst_gg = (const int*)d_in[3];
    const int* src_gt = (const int*)d_in[4];
    const int* dst_gt = (const int*)d_in[5];
    const int* src_tg = (const int*)d_in[6];
    const int* dst_tg = (const int*)d_in[7];
    const float* Wn_gg = (const float*)d_in[8];
    const float* Ws_gg = (const float*)d_in[9];
    const float* b_gg  = (const float*)d_in[10];
    const float* Wn_gt = (const float*)d_in[11];
    const float* Ws_gt = (const float*)d_in[12];
    const float* b_gt  = (const float*)d_in[13];
    const float* Wn_tg = (const float*)d_in[14];
    const float* Ws_tg = (const float*)d_in[15];
    const float* b_tg  = (const float*)d_in[16];

    const int nE_gg = in_sizes[2];
    const int nE_gt = in_sizes[4];
    const int nE_tg = in_sizes[6];
    const int nE_total = nE_gg + nE_gt + nE_tg;

    float* out_gene  = (float*)d_out;
    float* out_trait = (float*)d_out + (size_t)NG * D;

    // ws: xb_gene[(NG+1)*D] | xb_trait[(NT+1)*D] | aggA | aggB | aggC |
    //   WpG | WpT | biasG | biasT | off[NSEG] | dend[NSEG] | bcursor[256] |
    //   sorted[NBUCK*CAP] | binned[NBUCK*CAP]
    unsigned short* xb_gene  = (unsigned short*)d_ws;
    unsigned short* xb_trait = xb_gene + (size_t)(NG + 1) * D;
    unsigned short* aggA = xb_trait + (size_t)(NT + 1) * D;
    unsigned short* aggB = aggA + (size_t)NG * D;
    unsigned short* aggC = aggB + (size_t)NG * D;
    char* p = (char*)(aggC + (size_t)NT * D);
    unsigned short* WpG = (unsigned short*)p;  p += 24 * 4 * 64 * 8 * sizeof(unsigned short);
    unsigned short* WpT = (unsigned short*)p;  p += 16 * 4 * 64 * 8 * sizeof(unsigned short);
    float* biasG = (float*)p;                  p += D * sizeof(float);
    float* biasT = (float*)p;                  p += D * sizeof(float);
    int* off     = (int*)p;                    p += (size_t)NSEG * sizeof(int);
    int* dend    = (int*)p;                    p += (size_t)NSEG * sizeof(int);
    int* bcursor = (int*)p;                    p += NBUCK * sizeof(int);
    int* sorted  = (int*)p;                    p += (size_t)NBUCK * CAP * sizeof(int);
    int2* binned = (int2*)p;

    // 1) setup: feature tables + weight pack + zero bucket cursors
    const int setup_blocks = (CVT8 + 10496 + NBUCK + 255) / 256;
    setup_kernel<<<setup_blocks, 256, 0, stream>>>(
        x_gene, x_trait, xb_gene, xb_trait,
        Ws_gg, Ws_tg, Wn_gg, Wn_tg, Ws_gt, Wn_gt, b_gg, b_tg, b_gt,
        WpG, WpT, biasG, biasT, bcursor);

    // 2) binning: single-pass scatter into fixed-capacity buckets, then
    //    per-bucket counting sort
    const int nWG = (nE_total + TILE - 1) / TILE;
    bscatter_kernel<<<nWG, 256, 0, stream>>>(
        src_gg, dst_gg, nE_gg, src_gt, dst_gt, nE_gt, src_tg, dst_tg,
        nE_total, bcursor, binned);
    bbuild_kernel<<<NBUCK, 256, 0, stream>>>(binned, bcursor, off, dend, sorted);

    // 3) fused aggregation over all 300k dst nodes (gg->aggA, gt->aggC, tg->aggB)
    agg_all_kernel<<<(NSEG + 15) / 16, 256, 0, stream>>>(
        xb_gene, xb_trait, off, dend, sorted, aggA, aggC, aggB);

    // 4) both output GEMMs in one launch
    const int GBb = ((NG + 31) / 32 + 15) / 16;   // 196
    const int TBb = ((NT + 31) / 32 + 15) / 16;   // 196
    gemm_all<<<GBb + TBb, 1024, 0, stream>>>(
        xb_gene, xb_trait, aggA, aggB, aggC, WpG, WpT, biasG, biasT,
        out_gene, out_trait, GBb);
}

// Round 13
// 176.022 us; speedup vs baseline: 1.6288x; 1.0503x over previous
//
#include <hip/hip_runtime.h>
#include <hip/hip_bf16.h>

// HeteroGCN: 3x SAGEConv(mean).
// R1-R8: CSR gather (no atomics), LDS-binning CSR build, bf16 MFMA GEMM with
//        K-concat + packed weights, bf16 feature tables.
// R9 (failed): agg-in-GEMM fusion -> 8% occupancy, reverted.
// R10: agg index-broadcast via __shfl; zero-row tail padding; one GEMM launch.
// R11: setup fuses cvt+weight-pack; bscan folded away.
// R12: fixed-capacity buckets (CAP=8192): bcount kernel + bucket-base scans deleted.
// R13: setup and bscatter are independent -> fused into ONE block-partitioned
//      kernel (blocks [0,nWG) scatter, rest do cvt/pack). Cursor zeroing moved
//      to a tiny 1-block pre-kernel. Pipeline: zero -> setup_scatter -> bbuild
//      -> agg -> gemm (5 dispatches, setup/scatter overlapped).

#define D 128
#define NG 100000
#define NT 100000
#define NSEG (NG + NT + NG)   // concatenated dst-node counters: gg | gt | tg

#define NBUCK 256
#define NPB   ((NSEG + NBUCK - 1) / NBUCK)   // 1172 seg-nodes per bucket
#define TILE  4096                            // edges per bscatter workgroup
#define CAP   8192                            // max edges per bucket (mean 5860)

typedef __bf16 bf16x8 __attribute__((ext_vector_type(8)));
typedef float f32x16 __attribute__((ext_vector_type(16)));
typedef float v2f __attribute__((ext_vector_type(2)));

static __device__ __forceinline__ unsigned short f2bf(float f) {
    return __builtin_bit_cast(unsigned short, (__bf16)f);
}
static __device__ __forceinline__ float bflo(unsigned int v) {
    return __builtin_bit_cast(float, v << 16);
}
static __device__ __forceinline__ float bfhi(unsigned int v) {
    return __builtin_bit_cast(float, v & 0xffff0000u);
}

// ---------------- tiny: zero bucket cursors ----------------
__global__ __launch_bounds__(256) void zero_kernel(int* __restrict__ bcursor)
{
    bcursor[threadIdx.x] = 0;
}

// ---------------- edge helpers ----------------
static __device__ __forceinline__ int edge_seg(
    int ge, const int* d0, int n0, const int* d1, int n1, const int* d2)
{
    if (ge < n0) return d0[ge];
    if (ge < n0 + n1) return NG + d1[ge - n0];
    return NG + NT + d2[ge - n0 - n1];
}
static __device__ __forceinline__ int edge_src(
    int ge, const int* s0, int n0, const int* s1, int n1, const int* s2)
{
    if (ge < n0) return s0[ge];
    if (ge < n0 + n1) return s1[ge - n0];
    return s2[ge - n0 - n1];
}

// ---------------- fused: bscatter (blocks [0,nWG)) + setup (rest) ----------------
#define CVT8 (((NG + 1) + (NT + 1)) * D / 8)
#define SETUP_ITEMS (CVT8 + 6144 + 4096 + 128 + 128)

__global__ __launch_bounds__(256) void setup_scatter_kernel(
    // bscatter args
    const int* __restrict__ s0, const int* __restrict__ d0, int n0,
    const int* __restrict__ s1, const int* __restrict__ d1, int n1,
    const int* __restrict__ s2, const int* __restrict__ d2, int nE,
    int* __restrict__ bcursor, int2* __restrict__ binned, int nWG,
    // setup args
    const float* __restrict__ xg, const float* __restrict__ xt,
    unsigned short* __restrict__ og, unsigned short* __restrict__ ot,
    const float* __restrict__ Ws_gg, const float* __restrict__ Ws_tg,
    const float* __restrict__ Wn_gg, const float* __restrict__ Wn_tg,
    const float* __restrict__ Ws_gt, const float* __restrict__ Wn_gt,
    const float* __restrict__ b_gg, const float* __restrict__ b_tg,
    const float* __restrict__ b_gt,
    unsigned short* __restrict__ WpG, unsigned short* __restrict__ WpT,
    float* __restrict__ biasG, float* __restrict__ biasT)
{
    __shared__ int2 stage[TILE];                                  // 32 KiB
    __shared__ int hist[NBUCK], scn[NBUCK], gbase[NBUCK], lcur[NBUCK];
    const int t = threadIdx.x;

    if ((int)blockIdx.x < nWG) {
        // ---- bscatter body: LDS multi-split, bucket base = b*CAP ----
        hist[t] = 0;
        __syncthreads();

        const int base = blockIdx.x * TILE;
        int mseg[TILE / 256], msrc[TILE / 256];
#pragma unroll
        for (int j = 0; j < TILE / 256; ++j) {
            const int ge = base + j * 256 + t;
            if (ge < nE) {
                mseg[j] = edge_seg(ge, d0, n0, d1, n1, d2);
                msrc[j] = edge_src(ge, s0, n0, s1, n1, s2);
                atomicAdd(&hist[mseg[j] / NPB], 1);
            } else mseg[j] = -1;
        }
        __syncthreads();

        // exclusive scan of per-WG histogram (for LDS reorder only)
        const int h = hist[t];
        scn[t] = h;
        __syncthreads();
        for (int sh = 1; sh < NBUCK; sh <<= 1) {
            int u = (t >= sh) ? scn[t - sh] : 0;
            __syncthreads();
            scn[t] += u;
            __syncthreads();
        }
        const int excl = scn[t] - h;
        __syncthreads();
        scn[t] = excl;
        lcur[t] = excl;
        if (h) gbase[t] = t * CAP + atomicAdd(&bcursor[t], h);
        __syncthreads();

#pragma unroll
        for (int j = 0; j < TILE / 256; ++j) {
            if (mseg[j] >= 0) {
                const int b = mseg[j] / NPB;
                const int pos = atomicAdd(&lcur[b], 1);
                stage[pos] = make_int2(msrc[j], mseg[j]);
            }
        }
        __syncthreads();

        const int cnt = min(TILE, nE - base);
        for (int slot = t; slot < cnt; slot += 256) {
            const int2 pr = stage[slot];
            const int b = pr.y / NPB;
            const int gpos = gbase[b] + (slot - scn[b]);
            if (gpos < (b + 1) * CAP)   // defensive: never cross bucket boundary
                binned[gpos] = pr;
        }
        return;
    }

    // ---- setup body: bf16 tables (+zero row) | weight pack | bias fold ----
    const int gid = (blockIdx.x - nWG) * 256 + t;
    if (gid < CVT8) {
        const int ng8 = (NG + 1) * D / 8;
        const float* x; unsigned short* o; int j, nreal8;
        if (gid < ng8) { x = xg; o = og; j = gid;       nreal8 = NG * D / 8; }
        else           { x = xt; o = ot; j = gid - ng8; nreal8 = NT * D / 8; }
        uint4 v = make_uint4(0, 0, 0, 0);
        if (j < nreal8) {
            const float4 f0 = ((const float4*)x)[j * 2];
            const float4 f1 = ((const float4*)x)[j * 2 + 1];
            v.x = (unsigned int)f2bf(f0.x) | ((unsigned int)f2bf(f0.y) << 16);
            v.y = (unsigned int)f2bf(f0.z) | ((unsigned int)f2bf(f0.w) << 16);
            v.z = (unsigned int)f2bf(f1.x) | ((unsigned int)f2bf(f1.y) << 16);
            v.w = (unsigned int)f2bf(f1.z) | ((unsigned int)f2bf(f1.w) << 16);
        }
        ((uint4*)o)[j] = v;
        return;
    }
    const int g2 = gid - CVT8;
    if (g2 < 6144) {                        // gene pack: 24 kt * 4 nt * 64 lanes
        const int lane = g2 & 63, nt = (g2 >> 6) & 3, kt = g2 >> 8;
        const int n = nt * 32 + (lane & 31);
        const int kb = kt * 16 + (lane >> 5) * 8;
        unsigned int pk[4];
#pragma unroll
        for (int jj = 0; jj < 4; ++jj) {
            unsigned int w2 = 0;
#pragma unroll
            for (int h = 0; h < 2; ++h) {
                const int k = kb + jj * 2 + h;
                float w;
                if (k < 128)      w = Ws_gg[k * D + n] + Ws_tg[k * D + n];
                else if (k < 256) w = Wn_gg[(k - 128) * D + n];
                else              w = Wn_tg[(k - 256) * D + n];
                w2 |= ((unsigned int)f2bf(w)) << (16 * h);
            }
            pk[jj] = w2;
        }
        *(uint4*)(WpG + (size_t)g2 * 8) = make_uint4(pk[0], pk[1], pk[2], pk[3]);
    } else if (g2 < 6144 + 4096) {          // trait pack: 16 kt * 4 nt * 64 lanes
        const int g = g2 - 6144;
        const int lane = g & 63, nt = (g >> 6) & 3, kt = g >> 8;
        const int n = nt * 32 + (lane & 31);
        const int kb = kt * 16 + (lane >> 5) * 8;
        unsigned int pk[4];
#pragma unroll
        for (int jj = 0; jj < 4; ++jj) {
            unsigned int w2 = 0;
#pragma unroll
            for (int h = 0; h < 2; ++h) {
                const int k = kb + jj * 2 + h;
                const float w = (k < 128) ? Ws_gt[k * D + n] : Wn_gt[(k - 128) * D + n];
                w2 |= ((unsigned int)f2bf(w)) << (16 * h);
            }
            pk[jj] = w2;
        }
        *(uint4*)(WpT + (size_t)g * 8) = make_uint4(pk[0], pk[1], pk[2], pk[3]);
    } else if (g2 < 10240 + 128) {
        const int i = g2 - 10240;
        biasG[i] = b_gg[i] + b_tg[i];
    } else if (g2 < 10368 + 128) {
        const int i = g2 - 10368;
        biasT[i] = b_gt[i];
    }
}

// ---------------- bbuild: per-bucket counting sort in LDS ----------------
__global__ __launch_bounds__(256) void bbuild_kernel(
    const int2* __restrict__ binned, const int* __restrict__ bcursor,
    int* __restrict__ off, int* __restrict__ dend, int* __restrict__ sorted)
{
    constexpr int CH = (NPB + 255) / 256;   // 5
    __shared__ int ldeg[NPB];
    __shared__ int loff[NPB];
    __shared__ int psum[256];
    const int t = threadIdx.x;
    const int b = blockIdx.x;
    const int ebase = b * CAP;
    const int ecnt = min(bcursor[b], CAP);

    const int n0 = b * NPB;
    const int NL = min(NSEG - n0, NPB);

    for (int i = t; i < NL; i += 256) ldeg[i] = 0;
    __syncthreads();
    for (int e = t; e < ecnt; e += 256)
        atomicAdd(&ldeg[binned[ebase + e].y - n0], 1);
    __syncthreads();

    int s = 0;
#pragma unroll
    for (int k = 0; k < CH; ++k) {
        const int i = t * CH + k;
        if (i < NL) s += ldeg[i];
    }
    psum[t] = s;
    __syncthreads();
    for (int sh = 1; sh < 256; sh <<= 1) {
        int u = (t >= sh) ? psum[t - sh] : 0;
        __syncthreads();
        psum[t] += u;
        __syncthreads();
    }
    int run = psum[t] - s;
#pragma unroll
    for (int k = 0; k < CH; ++k) {
        const int i = t * CH + k;
        if (i < NL) { loff[i] = run; run += ldeg[i]; }
    }
    __syncthreads();

    for (int i = t; i < NL; i += 256) {
        off[n0 + i]  = ebase + loff[i];
        dend[n0 + i] = ebase + loff[i] + ldeg[i];
    }
    __syncthreads();

    for (int e = t; e < ecnt; e += 256) {
        const int2 pr = binned[ebase + e];
        const int slot = atomicAdd(&loff[pr.y - n0], 1);
        sorted[ebase + slot] = pr.x;
    }
}

// ---------------- aggregation: idx-broadcast gather, packed f32 accumulate ----------------
__global__ __launch_bounds__(256) void agg_all_kernel(
    const unsigned short* __restrict__ xg, const unsigned short* __restrict__ xt,
    const int* __restrict__ off, const int* __restrict__ dend,
    const int* __restrict__ sorted,
    unsigned short* __restrict__ aggA, unsigned short* __restrict__ aggC,
    unsigned short* __restrict__ aggB)
{
    const int t = threadIdx.x;
    const int node = blockIdx.x * 16 + (t >> 4);
    if (node >= NSEG) return;
    const int l = t & 15;
    const int gb = (t & 63) & ~15;   // group base lane within wave
    const int s0 = off[node];
    const int s1 = dend[node];

    const unsigned short* xb;
    unsigned short* out;
    int local, zrow;
    if (node < NG)           { xb = xg; out = aggA; local = node;           zrow = NG; }
    else if (node < NG + NT) { xb = xg; out = aggC; local = node - NG;      zrow = NG; }
    else                     { xb = xt; out = aggB; local = node - NG - NT; zrow = NT; }

    v2f A0 = (v2f){0.f, 0.f}, A1 = (v2f){0.f, 0.f};
    v2f A2 = (v2f){0.f, 0.f}, A3 = (v2f){0.f, 0.f};

    for (int e = s0; e < s1; e += 16) {
        const int cnt = min(s1 - e, 16);
        const int myidx = sorted[e + min(l, cnt - 1)];
#pragma unroll
        for (int j = 0; j < 16; j += 4) {
            if (j < cnt) {
                const int i0 = __shfl(myidx, gb + j, 64);
                const int i1 = (j + 1 < cnt) ? __shfl(myidx, gb + j + 1, 64) : zrow;
                const int i2 = (j + 2 < cnt) ? __shfl(myidx, gb + j + 2, 64) : zrow;
                const int i3 = (j + 3 < cnt) ? __shfl(myidx, gb + j + 3, 64) : zrow;
                const uint4 v0 = *(const uint4*)(xb + (size_t)i0 * D + l * 8);
                const uint4 v1 = *(const uint4*)(xb + (size_t)i1 * D + l * 8);
                const uint4 v2 = *(const uint4*)(xb + (size_t)i2 * D + l * 8);
                const uint4 v3 = *(const uint4*)(xb + (size_t)i3 * D + l * 8);
                A0 += (v2f){bflo(v0.x), bfhi(v0.x)};
                A1 += (v2f){bflo(v0.y), bfhi(v0.y)};
                A2 += (v2f){bflo(v0.z), bfhi(v0.z)};
                A3 += (v2f){bflo(v0.w), bfhi(v0.w)};
                A0 += (v2f){bflo(v1.x), bfhi(v1.x)};
                A1 += (v2f){bflo(v1.y), bfhi(v1.y)};
                A2 += (v2f){bflo(v1.z), bfhi(v1.z)};
                A3 += (v2f){bflo(v1.w), bfhi(v1.w)};
                A0 += (v2f){bflo(v2.x), bfhi(v2.x)};
                A1 += (v2f){bflo(v2.y), bfhi(v2.y)};
                A2 += (v2f){bflo(v2.z), bfhi(v2.z)};
                A3 += (v2f){bflo(v2.w), bfhi(v2.w)};
                A0 += (v2f){bflo(v3.x), bfhi(v3.x)};
                A1 += (v2f){bflo(v3.y), bfhi(v3.y)};
                A2 += (v2f){bflo(v3.z), bfhi(v3.z)};
                A3 += (v2f){bflo(v3.w), bfhi(v3.w)};
            }
        }
    }

    const float inv = 1.0f / (float)max(s1 - s0, 1);
    uint4 o;
    o.x = (unsigned int)f2bf(A0.x * inv) | ((unsigned int)f2bf(A0.y * inv) << 16);
    o.y = (unsigned int)f2bf(A1.x * inv) | ((unsigned int)f2bf(A1.y * inv) << 16);
    o.z = (unsigned int)f2bf(A2.x * inv) | ((unsigned int)f2bf(A2.y * inv) << 16);
    o.w = (unsigned int)f2bf(A3.x * inv) | ((unsigned int)f2bf(A3.y * inv) << 16);
    *(uint4*)(out + (size_t)local * D + l * 8) = o;
}

// ---------------- MFMA GEMM, both outputs in one launch ----------------
__global__ __launch_bounds__(1024) void gemm_all(
    const unsigned short* __restrict__ xbG, const unsigned short* __restrict__ xbT,
    const unsigned short* __restrict__ aggA, const unsigned short* __restrict__ aggB,
    const unsigned short* __restrict__ aggC,
    const unsigned short* __restrict__ WpG, const unsigned short* __restrict__ WpT,
    const float* __restrict__ biasG, const float* __restrict__ biasT,
    float* __restrict__ outG, float* __restrict__ outT, int GB)
{
    __shared__ unsigned short WL[8 * 4 * 64 * 8];   // 32 KiB: one source slice
    const int t = threadIdx.x;
    const int wid = t >> 6, lane = t & 63;
    const int lm = lane & 31, l5 = lane >> 5;

    const bool isG = (int)blockIdx.x < GB;
    const int bloc = isG ? blockIdx.x : blockIdx.x - GB;
    const int M = isG ? NG : NT;
    const int nsrc = isG ? 3 : 2;
    const unsigned short* A0 = isG ? xbG : xbT;
    const unsigned short* A1 = isG ? aggA : aggC;
    const unsigned short* A2 = aggB;
    const unsigned short* Wpack = isG ? WpG : WpT;
    const float* bias = isG ? biasG : biasT;
    float* out = isG ? outG : outT;

    const int tile = bloc * 16 + wid;
    const bool active = tile * 32 < M;
    const int m = tile * 32 + lm;

    f32x16 acc[4];
    if (active) {
#pragma unroll
        for (int nt = 0; nt < 4; ++nt) {
#pragma unroll
            for (int q = 0; q < 4; ++q) {
                const float4 bq = *(const float4*)&bias[nt * 32 + 4 * l5 + 8 * q];
                acc[nt][4 * q + 0] = bq.x; acc[nt][4 * q + 1] = bq.y;
                acc[nt][4 * q + 2] = bq.z; acc[nt][4 * q + 3] = bq.w;
            }
        }
    }

    const uint4* wg = (const uint4*)Wpack;
    uint4* wl = (uint4*)WL;

#pragma unroll 1
    for (int s = 0; s < nsrc; ++s) {
        __syncthreads();
        wl[t]        = wg[(size_t)s * 2048 + t];
        wl[t + 1024] = wg[(size_t)s * 2048 + t + 1024];
        __syncthreads();
        if (!active) continue;
        const unsigned short* ag = (s == 0) ? A0 : ((s == 1) ? A1 : A2);
        const unsigned short* ar = ag + (size_t)m * D + l5 * 8;
#pragma unroll
        for (int kt = 0; kt < 8; ++kt) {
            const bf16x8 a = *(const bf16x8*)(ar + kt * 16);
#pragma unroll
            for (int nt = 0; nt < 4; ++nt) {
                const bf16x8 b = *(const bf16x8*)&WL[((kt * 4 + nt) * 64 + lane) * 8];
                acc[nt] = __builtin_amdgcn_mfma_f32_32x32x16_bf16(b, a, acc[nt], 0, 0, 0);
            }
        }
    }

    if (active) {
        float* orow = out + (size_t)m * D;
#pragma unroll
        for (int nt = 0; nt < 4; ++nt) {
            float* p = orow + nt * 32 + 4 * l5;
            *(float4*)(p + 0)  = make_float4(acc[nt][0],  acc[nt][1],  acc[nt][2],  acc[nt][3]);
            *(float4*)(p + 8)  = make_float4(acc[nt][4],  acc[nt][5],  acc[nt][6],  acc[nt][7]);
            *(float4*)(p + 16) = make_float4(acc[nt][8],  acc[nt][9],  acc[nt][10], acc[nt][11]);
            *(float4*)(p + 24) = make_float4(acc[nt][12], acc[nt][13], acc[nt][14], acc[nt][15]);
        }
    }
}

extern "C" void kernel_launch(void* const* d_in, const int* in_sizes, int n_in,
                              void* d_out, int out_size, void* d_ws, size_t ws_size,
                              hipStream_t stream)
{
    const float* x_gene  = (const float*)d_in[0];
    const float* x_trait = (const float*)d_in[1];
    const int* src_gg = (const int*)d_in[2];
    const int* dst_gg = (const int*)d_in[3];
    const int* src_gt = (const int*)d_in[4];
    const int* dst_gt = (const int*)d_in[5];
    const int* src_tg = (const int*)d_in[6];
    const int* dst_tg = (const int*)d_in[7];
    const float* Wn_gg = (const float*)d_in[8];
    const float* Ws_gg = (const float*)d_in[9];
    const float* b_gg  = (const float*)d_in[10];
    const float* Wn_gt = (const float*)d_in[11];
    const float* Ws_gt = (const float*)d_in[12];
    const float* b_gt  = (const float*)d_in[13];
    const float* Wn_tg = (const float*)d_in[14];
    const float* Ws_tg = (const float*)d_in[15];
    const float* b_tg  = (const float*)d_in[16];

    const int nE_gg = in_sizes[2];
    const int nE_gt = in_sizes[4];
    const int nE_tg = in_sizes[6];
    const int nE_total = nE_gg + nE_gt + nE_tg;

    float* out_gene  = (float*)d_out;
    float* out_trait = (float*)d_out + (size_t)NG * D;

    // ws: xb_gene[(NG+1)*D] | xb_trait[(NT+1)*D] | aggA | aggB | aggC |
    //   WpG | WpT | biasG | biasT | off[NSEG] | dend[NSEG] | bcursor[256] |
    //   sorted[NBUCK*CAP] | binned[NBUCK*CAP]
    unsigned short* xb_gene  = (unsigned short*)d_ws;
    unsigned short* xb_trait = xb_gene + (size_t)(NG + 1) * D;
    unsigned short* aggA = xb_trait + (size_t)(NT + 1) * D;
    unsigned short* aggB = aggA + (size_t)NG * D;
    unsigned short* aggC = aggB + (size_t)NG * D;
    char* p = (char*)(aggC + (size_t)NT * D);
    unsigned short* WpG = (unsigned short*)p;  p += 24 * 4 * 64 * 8 * sizeof(unsigned short);
    unsigned short* WpT = (unsigned short*)p;  p += 16 * 4 * 64 * 8 * sizeof(unsigned short);
    float* biasG = (float*)p;                  p += D * sizeof(float);
    float* biasT = (float*)p;                  p += D * sizeof(float);
    int* off     = (int*)p;                    p += (size_t)NSEG * sizeof(int);
    int* dend    = (int*)p;                    p += (size_t)NSEG * sizeof(int);
    int* bcursor = (int*)p;                    p += NBUCK * sizeof(int);
    int* sorted  = (int*)p;                    p += (size_t)NBUCK * CAP * sizeof(int);
    int2* binned = (int2*)p;

    // 1) zero bucket cursors (must precede the fused kernel's scatter blocks)
    zero_kernel<<<1, 256, 0, stream>>>(bcursor);

    // 2) fused: edge binning (blocks [0,nWG)) + feature-table cvt + weight pack
    const int nWG = (nE_total + TILE - 1) / TILE;
    const int setup_blocks = (SETUP_ITEMS + 255) / 256;
    setup_scatter_kernel<<<nWG + setup_blocks, 256, 0, stream>>>(
        src_gg, dst_gg, nE_gg, src_gt, dst_gt, nE_gt, src_tg, dst_tg,
        nE_total, bcursor, binned, nWG,
        x_gene, x_trait, xb_gene, xb_trait,
        Ws_gg, Ws_tg, Wn_gg, Wn_tg, Ws_gt, Wn_gt, b_gg, b_tg, b_gt,
        WpG, WpT, biasG, biasT);

    // 3) per-bucket counting sort -> off/dend/sorted
    bbuild_kernel<<<NBUCK, 256, 0, stream>>>(binned, bcursor, off, dend, sorted);

    // 4) fused aggregation over all 300k dst nodes (gg->aggA, gt->aggC, tg->aggB)
    agg_all_kernel<<<(NSEG + 15) / 16, 256, 0, stream>>>(
        xb_gene, xb_trait, off, dend, sorted, aggA, aggC, aggB);

    // 5) both output GEMMs in one launch
    const int GBb = ((NG + 31) / 32 + 15) / 16;   // 196
    const int TBb = ((NT + 31) / 32 + 15) / 16;   // 196
    gemm_all<<<GBb + TBb, 1024, 0, stream>>>(
        xb_gene, xb_trait, aggA, aggB, aggC, WpG, WpT, biasG, biasT,
        out_gene, out_trait, GBb);
}

// Round 15
// 173.263 us; speedup vs baseline: 1.6548x; 1.0159x over previous
//
#include <hip/hip_runtime.h>
#include <hip/hip_bf16.h>

// HeteroGCN: 3x SAGEConv(mean).
// R1-R8: CSR gather (no atomics), LDS-binning CSR build, bf16 MFMA GEMM with
//        K-concat + packed weights, bf16 feature tables.
// R9 (failed): agg-in-GEMM fusion -> 8% occupancy, reverted.
// R10: agg index-broadcast via __shfl; zero-row tail padding; one GEMM launch.
// R11: setup fuses cvt+weight-pack; bscan folded away.
// R12: fixed-capacity buckets: bcount kernel + bucket-base scans deleted.
// R13: setup and bscatter fused into one block-partitioned kernel.
// R14 (failed): per-(bucket,WG) cells with CAPW=64 — WRONG: a 4096-edge tile is
//      one etype, spanning only ~85 buckets -> lambda=48/cell, 64 = +2.3 sigma
//      -> ~0.7% of cells overflowed, edges dropped (absmax 2.05).
// R15: CAPW=128 (lambda=48 + 11.6 sigma, tail ~ e^-40). Same R14 structure:
//      deterministic cells (no cursor atomics, no zero kernel, 4 dispatches),
//      512-thread GEMM for gene/trait tail balance.

#define D 128
#define NG 100000
#define NT 100000
#define NSEG (NG + NT + NG)   // concatenated dst-node counters: gg | gt | tg

#define NBUCK 256
#define NPB   ((NSEG + NBUCK - 1) / NBUCK)   // 1172 seg-nodes per bucket
#define TILE  4096                            // edges per bscatter workgroup
#define CAP   8192                            // max edges per bucket (mean 5860, +30 sigma)
#define CAPW  128                             // max edges per (bucket, WG) cell (mean 48, +11.6 sigma)

typedef __bf16 bf16x8 __attribute__((ext_vector_type(8)));
typedef float f32x16 __attribute__((ext_vector_type(16)));
typedef float v2f __attribute__((ext_vector_type(2)));

static __device__ __forceinline__ unsigned short f2bf(float f) {
    return __builtin_bit_cast(unsigned short, (__bf16)f);
}
static __device__ __forceinline__ float bflo(unsigned int v) {
    return __builtin_bit_cast(float, v << 16);
}
static __device__ __forceinline__ float bfhi(unsigned int v) {
    return __builtin_bit_cast(float, v & 0xffff0000u);
}

// ---------------- edge helpers ----------------
static __device__ __forceinline__ int edge_seg(
    int ge, const int* d0, int n0, const int* d1, int n1, const int* d2)
{
    if (ge < n0) return d0[ge];
    if (ge < n0 + n1) return NG + d1[ge - n0];
    return NG + NT + d2[ge - n0 - n1];
}
static __device__ __forceinline__ int edge_src(
    int ge, const int* s0, int n0, const int* s1, int n1, const int* s2)
{
    if (ge < n0) return s0[ge];
    if (ge < n0 + n1) return s1[ge - n0];
    return s2[ge - n0 - n1];
}

// ---------------- fused: bscatter (blocks [0,nWG)) + setup (rest) ----------------
#define CVT8 (((NG + 1) + (NT + 1)) * D / 8)
#define SETUP_ITEMS (CVT8 + 6144 + 4096 + 128 + 128)

__global__ __launch_bounds__(256) void setup_scatter_kernel(
    // bscatter args
    const int* __restrict__ s0, const int* __restrict__ d0, int n0,
    const int* __restrict__ s1, const int* __restrict__ d1, int n1,
    const int* __restrict__ s2, const int* __restrict__ d2, int nE,
    int* __restrict__ cellcnt, int2* __restrict__ binned, int nWG,
    // setup args
    const float* __restrict__ xg, const float* __restrict__ xt,
    unsigned short* __restrict__ og, unsigned short* __restrict__ ot,
    const float* __restrict__ Ws_gg, const float* __restrict__ Ws_tg,
    const float* __restrict__ Wn_gg, const float* __restrict__ Wn_tg,
    const float* __restrict__ Ws_gt, const float* __restrict__ Wn_gt,
    const float* __restrict__ b_gg, const float* __restrict__ b_tg,
    const float* __restrict__ b_gt,
    unsigned short* __restrict__ WpG, unsigned short* __restrict__ WpT,
    float* __restrict__ biasG, float* __restrict__ biasT)
{
    __shared__ int2 stage[TILE];                                  // 32 KiB
    __shared__ int hist[NBUCK], scn[NBUCK], lcur[NBUCK];
    const int t = threadIdx.x;

    if ((int)blockIdx.x < nWG) {
        // ---- bscatter body: LDS multi-split into deterministic cells ----
        hist[t] = 0;
        __syncthreads();

        const int base = blockIdx.x * TILE;
        int mseg[TILE / 256], msrc[TILE / 256];
#pragma unroll
        for (int j = 0; j < TILE / 256; ++j) {
            const int ge = base + j * 256 + t;
            if (ge < nE) {
                mseg[j] = edge_seg(ge, d0, n0, d1, n1, d2);
                msrc[j] = edge_src(ge, s0, n0, s1, n1, s2);
                atomicAdd(&hist[mseg[j] / NPB], 1);
            } else mseg[j] = -1;
        }
        __syncthreads();

        // cell count for bucket t (this WG) -- no global atomics needed
        const int h = hist[t];
        cellcnt[(size_t)t * nWG + blockIdx.x] = min(h, CAPW);

        // exclusive scan of per-WG histogram (for LDS reorder only)
        scn[t] = h;
        __syncthreads();
        for (int sh = 1; sh < NBUCK; sh <<= 1) {
            int u = (t >= sh) ? scn[t - sh] : 0;
            __syncthreads();
            scn[t] += u;
            __syncthreads();
        }
        const int excl = scn[t] - h;
        __syncthreads();
        scn[t] = excl;
        lcur[t] = excl;
        __syncthreads();

#pragma unroll
        for (int j = 0; j < TILE / 256; ++j) {
            if (mseg[j] >= 0) {
                const int b = mseg[j] / NPB;
                const int pos = atomicAdd(&lcur[b], 1);
                stage[pos] = make_int2(msrc[j], mseg[j]);
            }
        }
        __syncthreads();

        const int cnt = min(TILE, nE - base);
        for (int slot = t; slot < cnt; slot += 256) {
            const int2 pr = stage[slot];
            const int b = pr.y / NPB;
            const int pic = slot - scn[b];     // position within this WG's cell
            if (pic < CAPW)
                binned[((size_t)b * nWG + blockIdx.x) * CAPW + pic] = pr;
        }
        return;
    }

    // ---- setup body: bf16 tables (+zero row) | weight pack | bias fold ----
    const int gid = (blockIdx.x - nWG) * 256 + t;
    if (gid < CVT8) {
        const int ng8 = (NG + 1) * D / 8;
        const float* x; unsigned short* o; int j, nreal8;
        if (gid < ng8) { x = xg; o = og; j = gid;       nreal8 = NG * D / 8; }
        else           { x = xt; o = ot; j = gid - ng8; nreal8 = NT * D / 8; }
        uint4 v = make_uint4(0, 0, 0, 0);
        if (j < nreal8) {
            const float4 f0 = ((const float4*)x)[j * 2];
            const float4 f1 = ((const float4*)x)[j * 2 + 1];
            v.x = (unsigned int)f2bf(f0.x) | ((unsigned int)f2bf(f0.y) << 16);
            v.y = (unsigned int)f2bf(f0.z) | ((unsigned int)f2bf(f0.w) << 16);
            v.z = (unsigned int)f2bf(f1.x) | ((unsigned int)f2bf(f1.y) << 16);
            v.w = (unsigned int)f2bf(f1.z) | ((unsigned int)f2bf(f1.w) << 16);
        }
        ((uint4*)o)[j] = v;
        return;
    }
    const int g2 = gid - CVT8;
    if (g2 < 6144) {                        // gene pack: 24 kt * 4 nt * 64 lanes
        const int lane = g2 & 63, nt = (g2 >> 6) & 3, kt = g2 >> 8;
        const int n = nt * 32 + (lane & 31);
        const int kb = kt * 16 + (lane >> 5) * 8;
        unsigned int pk[4];
#pragma unroll
        for (int jj = 0; jj < 4; ++jj) {
            unsigned int w2 = 0;
#pragma unroll
            for (int h = 0; h < 2; ++h) {
                const int k = kb + jj * 2 + h;
                float w;
                if (k < 128)      w = Ws_gg[k * D + n] + Ws_tg[k * D + n];
                else if (k < 256) w = Wn_gg[(k - 128) * D + n];
                else              w = Wn_tg[(k - 256) * D + n];
                w2 |= ((unsigned int)f2bf(w)) << (16 * h);
            }
            pk[jj] = w2;
        }
        *(uint4*)(WpG + (size_t)g2 * 8) = make_uint4(pk[0], pk[1], pk[2], pk[3]);
    } else if (g2 < 6144 + 4096) {          // trait pack: 16 kt * 4 nt * 64 lanes
        const int g = g2 - 6144;
        const int lane = g & 63, nt = (g >> 6) & 3, kt = g >> 8;
        const int n = nt * 32 + (lane & 31);
        const int kb = kt * 16 + (lane >> 5) * 8;
        unsigned int pk[4];
#pragma unroll
        for (int jj = 0; jj < 4; ++jj) {
            unsigned int w2 = 0;
#pragma unroll
            for (int h = 0; h < 2; ++h) {
                const int k = kb + jj * 2 + h;
                const float w = (k < 128) ? Ws_gt[k * D + n] : Wn_gt[(k - 128) * D + n];
                w2 |= ((unsigned int)f2bf(w)) << (16 * h);
            }
            pk[jj] = w2;
        }
        *(uint4*)(WpT + (size_t)g * 8) = make_uint4(pk[0], pk[1], pk[2], pk[3]);
    } else if (g2 < 10240 + 128) {
        const int i = g2 - 10240;
        biasG[i] = b_gg[i] + b_tg[i];
    } else if (g2 < 10368 + 128) {
        const int i = g2 - 10368;
        biasT[i] = b_gt[i];
    }
}

// ---------------- bbuild: per-bucket counting sort from cells ----------------
__global__ __launch_bounds__(256) void bbuild_kernel(
    const int2* __restrict__ binned, const int* __restrict__ cellcnt, int nWG,
    int* __restrict__ off, int* __restrict__ dend, int* __restrict__ sorted)
{
    constexpr int CH = (NPB + 255) / 256;   // 5
    __shared__ int ldeg[NPB];
    __shared__ int loff[NPB];
    __shared__ int psum[256];
    const int t = threadIdx.x;
    const int b = blockIdx.x;
    const int n0 = b * NPB;
    const int NL = min(NSEG - n0, NPB);

    for (int i = t; i < NL; i += 256) ldeg[i] = 0;
    __syncthreads();

    // phase 1: per-node degree from this bucket's cells
    for (int w = t; w < nWG; w += 256) {
        const int c = min(cellcnt[(size_t)b * nWG + w], CAPW);
        const int2* cell = binned + ((size_t)b * nWG + w) * CAPW;
        for (int i = 0; i < c; ++i)
            atomicAdd(&ldeg[cell[i].y - n0], 1);
    }
    __syncthreads();

    // phase 2: block-wide exclusive scan over NL node degrees
    int s = 0;
#pragma unroll
    for (int k = 0; k < CH; ++k) {
        const int i = t * CH + k;
        if (i < NL) s += ldeg[i];
    }
    psum[t] = s;
    __syncthreads();
    for (int sh = 1; sh < 256; sh <<= 1) {
        int u = (t >= sh) ? psum[t - sh] : 0;
        __syncthreads();
        psum[t] += u;
        __syncthreads();
    }
    int run = psum[t] - s;
#pragma unroll
    for (int k = 0; k < CH; ++k) {
        const int i = t * CH + k;
        if (i < NL) { loff[i] = run; run += ldeg[i]; }
    }
    __syncthreads();

    const int ebase = b * CAP;
    for (int i = t; i < NL; i += 256) {
        off[n0 + i]  = ebase + loff[i];
        dend[n0 + i] = ebase + loff[i] + ldeg[i];
    }
    __syncthreads();

    // phase 3: scatter cells into per-node-contiguous sorted[]
    for (int w = t; w < nWG; w += 256) {
        const int c = min(cellcnt[(size_t)b * nWG + w], CAPW);
        const int2* cell = binned + ((size_t)b * nWG + w) * CAPW;
        for (int i = 0; i < c; ++i) {
            const int2 pr = cell[i];
            const int slot = atomicAdd(&loff[pr.y - n0], 1);
            sorted[ebase + slot] = pr.x;
        }
    }
}

// ---------------- aggregation: idx-broadcast gather, packed f32 accumulate ----------------
__global__ __launch_bounds__(256) void agg_all_kernel(
    const unsigned short* __restrict__ xg, const unsigned short* __restrict__ xt,
    const int* __restrict__ off, const int* __restrict__ dend,
    const int* __restrict__ sorted,
    unsigned short* __restrict__ aggA, unsigned short* __restrict__ aggC,
    unsigned short* __restrict__ aggB)
{
    const int t = threadIdx.x;
    const int node = blockIdx.x * 16 + (t >> 4);
    if (node >= NSEG) return;
    const int l = t & 15;
    const int gb = (t & 63) & ~15;   // group base lane within wave
    const int s0 = off[node];
    const int s1 = dend[node];

    const unsigned short* xb;
    unsigned short* out;
    int local, zrow;
    if (node < NG)           { xb = xg; out = aggA; local = node;           zrow = NG; }
    else if (node < NG + NT) { xb = xg; out = aggC; local = node - NG;      zrow = NG; }
    else                     { xb = xt; out = aggB; local = node - NG - NT; zrow = NT; }

    v2f A0 = (v2f){0.f, 0.f}, A1 = (v2f){0.f, 0.f};
    v2f A2 = (v2f){0.f, 0.f}, A3 = (v2f){0.f, 0.f};

    for (int e = s0; e < s1; e += 16) {
        const int cnt = min(s1 - e, 16);
        const int myidx = sorted[e + min(l, cnt - 1)];
#pragma unroll
        for (int j = 0; j < 16; j += 4) {
            if (j < cnt) {
                const int i0 = __shfl(myidx, gb + j, 64);
                const int i1 = (j + 1 < cnt) ? __shfl(myidx, gb + j + 1, 64) : zrow;
                const int i2 = (j + 2 < cnt) ? __shfl(myidx, gb + j + 2, 64) : zrow;
                const int i3 = (j + 3 < cnt) ? __shfl(myidx, gb + j + 3, 64) : zrow;
                const uint4 v0 = *(const uint4*)(xb + (size_t)i0 * D + l * 8);
                const uint4 v1 = *(const uint4*)(xb + (size_t)i1 * D + l * 8);
                const uint4 v2 = *(const uint4*)(xb + (size_t)i2 * D + l * 8);
                const uint4 v3 = *(const uint4*)(xb + (size_t)i3 * D + l * 8);
                A0 += (v2f){bflo(v0.x), bfhi(v0.x)};
                A1 += (v2f){bflo(v0.y), bfhi(v0.y)};
                A2 += (v2f){bflo(v0.z), bfhi(v0.z)};
                A3 += (v2f){bflo(v0.w), bfhi(v0.w)};
                A0 += (v2f){bflo(v1.x), bfhi(v1.x)};
                A1 += (v2f){bflo(v1.y), bfhi(v1.y)};
                A2 += (v2f){bflo(v1.z), bfhi(v1.z)};
                A3 += (v2f){bflo(v1.w), bfhi(v1.w)};
                A0 += (v2f){bflo(v2.x), bfhi(v2.x)};
                A1 += (v2f){bflo(v2.y), bfhi(v2.y)};
                A2 += (v2f){bflo(v2.z), bfhi(v2.z)};
                A3 += (v2f){bflo(v2.w), bfhi(v2.w)};
                A0 += (v2f){bflo(v3.x), bfhi(v3.x)};
                A1 += (v2f){bflo(v3.y), bfhi(v3.y)};
                A2 += (v2f){bflo(v3.z), bfhi(v3.z)};
                A3 += (v2f){bflo(v3.w), bfhi(v3.w)};
            }
        }
    }

    const float inv = 1.0f / (float)max(s1 - s0, 1);
    uint4 o;
    o.x = (unsigned int)f2bf(A0.x * inv) | ((unsigned int)f2bf(A0.y * inv) << 16);
    o.y = (unsigned int)f2bf(A1.x * inv) | ((unsigned int)f2bf(A1.y * inv) << 16);
    o.z = (unsigned int)f2bf(A2.x * inv) | ((unsigned int)f2bf(A2.y * inv) << 16);
    o.w = (unsigned int)f2bf(A3.x * inv) | ((unsigned int)f2bf(A3.y * inv) << 16);
    *(uint4*)(out + (size_t)local * D + l * 8) = o;
}

// ---------------- MFMA GEMM, both outputs in one launch (8 waves/block) ----------------
__global__ __launch_bounds__(512) void gemm_all(
    const unsigned short* __restrict__ xbG, const unsigned short* __restrict__ xbT,
    const unsigned short* __restrict__ aggA, const unsigned short* __restrict__ aggB,
    const unsigned short* __restrict__ aggC,
    const unsigned short* __restrict__ WpG, const unsigned short* __restrict__ WpT,
    const float* __restrict__ biasG, const float* __restrict__ biasT,
    float* __restrict__ outG, float* __restrict__ outT, int GB)
{
    __shared__ unsigned short WL[8 * 4 * 64 * 8];   // 32 KiB: one source slice
    const int t = threadIdx.x;
    const int wid = t >> 6, lane = t & 63;
    const int lm = lane & 31, l5 = lane >> 5;

    const bool isG = (int)blockIdx.x < GB;
    const int bloc = isG ? blockIdx.x : blockIdx.x - GB;
    const int M = isG ? NG : NT;
    const int nsrc = isG ? 3 : 2;
    const unsigned short* A0 = isG ? xbG : xbT;
    const unsigned short* A1 = isG ? aggA : aggC;
    const unsigned short* A2 = aggB;
    const unsigned short* Wpack = isG ? WpG : WpT;
    const float* bias = isG ? biasG : biasT;
    float* out = isG ? outG : outT;

    const int tile = bloc * 8 + wid;
    const bool active = tile * 32 < M;
    const int m = tile * 32 + lm;

    f32x16 acc[4];
    if (active) {
#pragma unroll
        for (int nt = 0; nt < 4; ++nt) {
#pragma unroll
            for (int q = 0; q < 4; ++q) {
                const float4 bq = *(const float4*)&bias[nt * 32 + 4 * l5 + 8 * q];
                acc[nt][4 * q + 0] = bq.x; acc[nt][4 * q + 1] = bq.y;
                acc[nt][4 * q + 2] = bq.z; acc[nt][4 * q + 3] = bq.w;
            }
        }
    }

    const uint4* wg = (const uint4*)Wpack;
    uint4* wl = (uint4*)WL;

#pragma unroll 1
    for (int s = 0; s < nsrc; ++s) {
        __syncthreads();
        wl[t]        = wg[(size_t)s * 2048 + t];
        wl[t + 512]  = wg[(size_t)s * 2048 + t + 512];
        wl[t + 1024] = wg[(size_t)s * 2048 + t + 1024];
        wl[t + 1536] = wg[(size_t)s * 2048 + t + 1536];
        __syncthreads();
        if (!active) continue;
        const unsigned short* ag = (s == 0) ? A0 : ((s == 1) ? A1 : A2);
        const unsigned short* ar = ag + (size_t)m * D + l5 * 8;
#pragma unroll
        for (int kt = 0; kt < 8; ++kt) {
            const bf16x8 a = *(const bf16x8*)(ar + kt * 16);
#pragma unroll
            for (int nt = 0; nt < 4; ++nt) {
                const bf16x8 b = *(const bf16x8*)&WL[((kt * 4 + nt) * 64 + lane) * 8];
                acc[nt] = __builtin_amdgcn_mfma_f32_32x32x16_bf16(b, a, acc[nt], 0, 0, 0);
            }
        }
    }

    if (active) {
        float* orow = out + (size_t)m * D;
#pragma unroll
        for (int nt = 0; nt < 4; ++nt) {
            float* p = orow + nt * 32 + 4 * l5;
            *(float4*)(p + 0)  = make_float4(acc[nt][0],  acc[nt][1],  acc[nt][2],  acc[nt][3]);
            *(float4*)(p + 8)  = make_float4(acc[nt][4],  acc[nt][5],  acc[nt][6],  acc[nt][7]);
            *(float4*)(p + 16) = make_float4(acc[nt][8],  acc[nt][9],  acc[nt][10], acc[nt][11]);
            *(float4*)(p + 24) = make_float4(acc[nt][12], acc[nt][13], acc[nt][14], acc[nt][15]);
        }
    }
}

extern "C" void kernel_launch(void* const* d_in, const int* in_sizes, int n_in,
                              void* d_out, int out_size, void* d_ws, size_t ws_size,
                              hipStream_t stream)
{
    const float* x_gene  = (const float*)d_in[0];
    const float* x_trait = (const float*)d_in[1];
    const int* src_gg = (const int*)d_in[2];
    const int* dst_gg = (const int*)d_in[3];
    const int* src_gt = (const int*)d_in[4];
    const int* dst_gt = (const int*)d_in[5];
    const int* src_tg = (const int*)d_in[6];
    const int* dst_tg = (const int*)d_in[7];
    const float* Wn_gg = (const float*)d_in[8];
    const float* Ws_gg = (const float*)d_in[9];
    const float* b_gg  = (const float*)d_in[10];
    const float* Wn_gt = (const float*)d_in[11];
    const float* Ws_gt = (const float*)d_in[12];
    const float* b_gt  = (const float*)d_in[13];
    const float* Wn_tg = (const float*)d_in[14];
    const float* Ws_tg = (const float*)d_in[15];
    const float* b_tg  = (const float*)d_in[16];

    const int nE_gg = in_sizes[2];
    const int nE_gt = in_sizes[4];
    const int nE_tg = in_sizes[6];
    const int nE_total = nE_gg + nE_gt + nE_tg;
    const int nWG = (nE_total + TILE - 1) / TILE;

    float* out_gene  = (float*)d_out;
    float* out_trait = (float*)d_out + (size_t)NG * D;

    // ws (~236 MB): xb_gene[(NG+1)*D] | xb_trait[(NT+1)*D] | aggA | aggB | aggC |
    //   WpG | WpT | biasG | biasT | off[NSEG] | dend[NSEG] |
    //   sorted[NBUCK*CAP] | cellcnt[NBUCK*nWG] | binned[NBUCK*nWG*CAPW]
    unsigned short* xb_gene  = (unsigned short*)d_ws;
    unsigned short* xb_trait = xb_gene + (size_t)(NG + 1) * D;
    unsigned short* aggA = xb_trait + (size_t)(NT + 1) * D;
    unsigned short* aggB = aggA + (size_t)NG * D;
    unsigned short* aggC = aggB + (size_t)NG * D;
    char* p = (char*)(aggC + (size_t)NT * D);
    unsigned short* WpG = (unsigned short*)p;  p += 24 * 4 * 64 * 8 * sizeof(unsigned short);
    unsigned short* WpT = (unsigned short*)p;  p += 16 * 4 * 64 * 8 * sizeof(unsigned short);
    float* biasG = (float*)p;                  p += D * sizeof(float);
    float* biasT = (float*)p;                  p += D * sizeof(float);
    int* off     = (int*)p;                    p += (size_t)NSEG * sizeof(int);
    int* dend    = (int*)p;                    p += (size_t)NSEG * sizeof(int);
    int* sorted  = (int*)p;                    p += (size_t)NBUCK * CAP * sizeof(int);
    int* cellcnt = (int*)p;                    p += (size_t)NBUCK * nWG * sizeof(int);
    int2* binned = (int2*)p;

    // 1) fused: edge binning into cells (blocks [0,nWG)) + cvt + weight pack
    const int setup_blocks = (SETUP_ITEMS + 255) / 256;
    setup_scatter_kernel<<<nWG + setup_blocks, 256, 0, stream>>>(
        src_gg, dst_gg, nE_gg, src_gt, dst_gt, nE_gt, src_tg, dst_tg,
        nE_total, cellcnt, binned, nWG,
        x_gene, x_trait, xb_gene, xb_trait,
        Ws_gg, Ws_tg, Wn_gg, Wn_tg, Ws_gt, Wn_gt, b_gg, b_tg, b_gt,
        WpG, WpT, biasG, biasT);

    // 2) per-bucket counting sort -> off/dend/sorted
    bbuild_kernel<<<NBUCK, 256, 0, stream>>>(binned, cellcnt, nWG, off, dend, sorted);

    // 3) fused aggregation over all 300k dst nodes (gg->aggA, gt->aggC, tg->aggB)
    agg_all_kernel<<<(NSEG + 15) / 16, 256, 0, stream>>>(
        xb_gene, xb_trait, off, dend, sorted, aggA, aggC, aggB);

    // 4) both output GEMMs in one launch (512-thread blocks, 8 waves)
    const int GBb = ((NG + 31) / 32 + 7) / 8;   // 391
    const int TBb = ((NT + 31) / 32 + 7) / 8;   // 391
    gemm_all<<<GBb + TBb, 512, 0, stream>>>(
        xb_gene, xb_trait, aggA, aggB, aggC, WpG, WpT, biasG, biasT,
        out_gene, out_trait, GBb);
}